// Round 3
// baseline (561.954 us; speedup 1.0000x reference)
//
#include <hip/hip_runtime.h>
#include <math.h>

// Problem dims (fixed)
#define B_ 4
#define T_ 1024
#define C_ 256
#define D_ 256
#define H_ 512
#define NH_ 8
#define HD_ 64
#define INTER_ 2048
#define L_ 4
#define CB_ 128   // context_backward; context_forward = 0

typedef short bf16x8 __attribute__((ext_vector_type(8)));
typedef float f32x4 __attribute__((ext_vector_type(4)));

__device__ __forceinline__ float gelu_exact(float x) {
    return 0.5f * x * (1.0f + erff(x * 0.70710678118654752f));
}

// fp32 -> bf16 round-to-nearest-even
__device__ __forceinline__ unsigned short f2bf(float f) {
    unsigned u = __float_as_uint(f);
    u += 0x7fffu + ((u >> 16) & 1u);
    return (unsigned short)(u >> 16);
}
__device__ __forceinline__ float bf2f(unsigned short h) {
    return __uint_as_float((unsigned)h << 16);
}

// XCD-chunked bijective block swizzle (T1), 3D grid aware. HW round-robins
// consecutive dispatch ids across 8 XCDs; remap so XCD k owns a CONTIGUOUS
// chunk of output tiles -> blocks sharing an A-panel co-reside on one XCD's
// L2. Requires nwg % 8 == 0 (all our grids satisfy this).
__device__ __forceinline__ void xcd_swz3(int& bx, int& by, int& bz) {
    const int gx  = gridDim.x, gy = gridDim.y;
    const int nwg = gx * gy * gridDim.z;
    int bid = (blockIdx.z * gy + blockIdx.y) * gx + blockIdx.x;
    bid = (bid & 7) * (nwg >> 3) + (bid >> 3);
    bx = bid % gx;
    int r = bid / gx;
    by = r % gy;
    bz = r / gy;
}

// ---------------------------------------------------------------------------
// bf16 MFMA GEMM, 64x64 tile, BK=64, XOR-swizzled LDS staging.
// ATOM=1: split-K mode -- blockIdx.z selects a K/gridDim.z slice; partials
// are fp32 global_atomic_add'ed into o0 (pre-initialized with residual+bias
// by ln_init_k). Grid (8,64,KS) = 8 blocks/CU at KS=4: fixes the 2-block/CU
// latency exposure of the deep-K N=512 down-projection (R1 lesson).
// ---------------------------------------------------------------------------
template<int ACT, int RES, int OBF, int SPLIT, int ATOM>
__global__ __launch_bounds__(256) void mm64_k(
    const unsigned short* __restrict__ A, const unsigned short* __restrict__ BT,
    const float* __restrict__ b0, const float* __restrict__ b1,
    const float* __restrict__ b2,
    const float* res,
    void* o0, void* o1, void* o2,
    const int M, const int N, const int K)
{
    __shared__ unsigned short As[64 * 64];
    __shared__ unsigned short Bs[64 * 64];

    int bx, by, bz; xcd_swz3(bx, by, bz);

    const int tid  = threadIdx.x;
    const int lane = tid & 63;
    const int w    = tid >> 6;
    const int m0   = by * 64;
    const int n0   = bx * 64;
    const int wm   = (w >> 1) * 32;
    const int wn   = (w & 1) * 32;
    const int l16  = lane & 15;
    const int g16  = lane >> 4;

    f32x4 acc[2][2] = {};

    const unsigned short* Abase = A  + (size_t)m0 * K;
    const unsigned short* Bbase = BT + (size_t)n0 * K;

    // staging chunks: c0 = w*64+lane (rows 8w..8w+7), c1 = c0+256 (rows 32..63)
    const int c0 = (w << 6) + lane;
    const int c1 = c0 + 256;
    const int r0c = c0 >> 3, g0c = c0 & 7, gk0 = g0c ^ (r0c & 7);
    const int r1c = c1 >> 3, g1c = c1 & 7, gk1 = g1c ^ (r1c & 7);

    const int Kslice = ATOM ? (K / (int)gridDim.z) : K;
    const int kbeg   = ATOM ? bz * Kslice : 0;
    const int kend   = kbeg + Kslice;

    for (int k0 = kbeg; k0 < kend; k0 += 64) {
        __syncthreads();
        __builtin_amdgcn_global_load_lds(
            (const __attribute__((address_space(1))) unsigned*)(Abase + (size_t)r0c * K + k0 + gk0 * 8),
            (__attribute__((address_space(3))) unsigned*)(As + (size_t)(w << 6) * 8), 16, 0, 0);
        __builtin_amdgcn_global_load_lds(
            (const __attribute__((address_space(1))) unsigned*)(Abase + (size_t)r1c * K + k0 + gk1 * 8),
            (__attribute__((address_space(3))) unsigned*)(As + (size_t)(256 + (w << 6)) * 8), 16, 0, 0);
        __builtin_amdgcn_global_load_lds(
            (const __attribute__((address_space(1))) unsigned*)(Bbase + (size_t)r0c * K + k0 + gk0 * 8),
            (__attribute__((address_space(3))) unsigned*)(Bs + (size_t)(w << 6) * 8), 16, 0, 0);
        __builtin_amdgcn_global_load_lds(
            (const __attribute__((address_space(1))) unsigned*)(Bbase + (size_t)r1c * K + k0 + gk1 * 8),
            (__attribute__((address_space(3))) unsigned*)(Bs + (size_t)(256 + (w << 6)) * 8), 16, 0, 0);
        __syncthreads();

#pragma unroll
        for (int kk = 0; kk < 2; ++kk) {
            const int kf = kk * 4 + g16;            // global k-group 0..7
            const int sw = (kf ^ (l16 & 7)) * 8;    // swizzled ushort offset
            bf16x8 a[2], b[2];
#pragma unroll
            for (int t = 0; t < 2; ++t)
                a[t] = *(const bf16x8*)&As[(wm + t * 16 + l16) * 64 + sw];
#pragma unroll
            for (int t = 0; t < 2; ++t)
                b[t] = *(const bf16x8*)&Bs[(wn + t * 16 + l16) * 64 + sw];
#pragma unroll
            for (int i = 0; i < 2; ++i)
#pragma unroll
                for (int j = 0; j < 2; ++j)
                    acc[i][j] = __builtin_amdgcn_mfma_f32_16x16x32_bf16(a[i], b[j], acc[i][j], 0, 0, 0);
        }
    }

    if (ATOM) {
        // split-K partial: atomic accumulate into pre-initialized fp32 out.
        float* out = (float*)o0;
#pragma unroll
        for (int i = 0; i < 2; ++i) {
            const int gmb = m0 + wm + i * 16 + g16 * 4;
#pragma unroll
            for (int j = 0; j < 2; ++j) {
                const int gn = n0 + wn + j * 16 + l16;
#pragma unroll
                for (int r = 0; r < 4; ++r)
                    atomicAdd(&out[(size_t)(gmb + r) * N + gn], acc[i][j][r]);
            }
        }
        return;
    }

    if (OBF || SPLIT) {
        __syncthreads();
        unsigned short* Eb = ((w < 2) ? As : Bs) + (w & 1) * 1024;
        const int row16 = lane >> 2;
        const int cg    = lane & 3;

        const int gnb   = n0 + wn;
        const int which = SPLIT ? (gnb >> 9) : 0;
        const int lnb   = SPLIT ? (gnb & 511) : gnb;
        const int ldo   = SPLIT ? 512 : N;
        unsigned short* oo = SPLIT
            ? ((which == 0) ? (unsigned short*)o0 : (which == 1) ? (unsigned short*)o1 : (unsigned short*)o2)
            : (unsigned short*)o0;
        const float* bb = SPLIT ? ((which == 0) ? b0 : (which == 1) ? b1 : b2) : b0;
        const float scale = (SPLIT && which == 0) ? 0.125f : 1.0f;

#pragma unroll
        for (int i = 0; i < 2; ++i) {
#pragma unroll
            for (int j = 0; j < 2; ++j) {
                const float bv = bb[lnb + j * 16 + l16];
#pragma unroll
                for (int r = 0; r < 4; ++r) {
                    float cv = acc[i][j][r] + bv;
                    if (ACT) cv = gelu_exact(cv);
                    if (SPLIT) cv *= scale;
                    Eb[(g16 * 4 + r) * 40 + j * 16 + l16] = f2bf(cv);
                }
            }
            const int grow0 = m0 + wm + i * 16 + row16;
#pragma unroll
            for (int s = 0; s < 2; ++s) {
                ushort4 t4 = *(const ushort4*)&Eb[row16 * 40 + s * 16 + cg * 4];
                *(ushort4*)&oo[(size_t)grow0 * ldo + lnb + s * 16 + cg * 4] = t4;
            }
        }
        return;
    }

    // fp32 out epilogue (scalar 4B stores = full 64B runs per 16 lanes)
#pragma unroll
    for (int i = 0; i < 2; ++i) {
        const int gmb = m0 + wm + i * 16 + g16 * 4;
#pragma unroll
        for (int j = 0; j < 2; ++j) {
            const int gn = n0 + wn + j * 16 + l16;
            const float bv = b0[gn];
#pragma unroll
            for (int r = 0; r < 4; ++r) {
                float cv = acc[i][j][r] + bv;
                if (ACT) cv = gelu_exact(cv);
                if (RES) cv += res[(size_t)(gmb + r) * 512 + gn];
                ((float*)o0)[(size_t)(gmb + r) * N + gn] = cv;
            }
        }
    }
}

// ---------------------------------------------------------------------------
// bf16 MFMA GEMM, 128x64 tile, BK=64. For wide-N GEMMs (QKV N=1536 grid 768,
// up N=2048 grid 1024 -> 3-4 blocks/CU) where the deeper 16 MFMA : 12 ds_read
// K-step pays without collapsing grid parallelism.
// ---------------------------------------------------------------------------
template<int ACT, int RES, int OBF, int SPLIT>
__global__ __launch_bounds__(256) void mm128_k(
    const unsigned short* __restrict__ A, const unsigned short* __restrict__ BT,
    const float* __restrict__ b0, const float* __restrict__ b1,
    const float* __restrict__ b2,
    const float* res,
    void* o0, void* o1, void* o2,
    const int M, const int N, const int K)
{
    __shared__ unsigned short As[128 * 64];
    __shared__ unsigned short Bs[64 * 64];

    int bx, by, bz; xcd_swz3(bx, by, bz);

    const int tid  = threadIdx.x;
    const int lane = tid & 63;
    const int w    = tid >> 6;
    const int m0   = by * 128;
    const int n0   = bx * 64;
    const int wm   = (w >> 1) * 64;       // 0 or 64
    const int wn   = (w & 1) * 32;        // 0 or 32
    const int l16  = lane & 15;
    const int g16  = lane >> 4;

    f32x4 acc[4][2] = {};

    const unsigned short* Abase = A  + (size_t)m0 * K;
    const unsigned short* Bbase = BT + (size_t)n0 * K;

    for (int k0 = 0; k0 < K; k0 += 64) {
        __syncthreads();
        // A tile: 128 rows x 64 cols = 1024 16B chunks, 4 issues/thread
#pragma unroll
        for (int it = 0; it < 4; ++it) {
            const int c = it * 256 + tid;
            const int rc = c >> 3, gk = (c & 7) ^ (rc & 7);
            __builtin_amdgcn_global_load_lds(
                (const __attribute__((address_space(1))) unsigned*)(Abase + (size_t)rc * K + k0 + gk * 8),
                (__attribute__((address_space(3))) unsigned*)(As + (size_t)(it * 256 + (w << 6)) * 8), 16, 0, 0);
        }
        // B tile: 64 rows x 64 cols, 2 issues/thread
#pragma unroll
        for (int it = 0; it < 2; ++it) {
            const int c = it * 256 + tid;
            const int rc = c >> 3, gk = (c & 7) ^ (rc & 7);
            __builtin_amdgcn_global_load_lds(
                (const __attribute__((address_space(1))) unsigned*)(Bbase + (size_t)rc * K + k0 + gk * 8),
                (__attribute__((address_space(3))) unsigned*)(Bs + (size_t)(it * 256 + (w << 6)) * 8), 16, 0, 0);
        }
        __syncthreads();

#pragma unroll
        for (int kk = 0; kk < 2; ++kk) {
            const int kf = kk * 4 + g16;            // global k-group 0..7
            const int sw = (kf ^ (l16 & 7)) * 8;    // swizzled ushort offset
            bf16x8 a[4], b[2];
#pragma unroll
            for (int t = 0; t < 4; ++t)
                a[t] = *(const bf16x8*)&As[(wm + t * 16 + l16) * 64 + sw];
#pragma unroll
            for (int t = 0; t < 2; ++t)
                b[t] = *(const bf16x8*)&Bs[(wn + t * 16 + l16) * 64 + sw];
#pragma unroll
            for (int i = 0; i < 4; ++i)
#pragma unroll
                for (int j = 0; j < 2; ++j)
                    acc[i][j] = __builtin_amdgcn_mfma_f32_16x16x32_bf16(a[i], b[j], acc[i][j], 0, 0, 0);
        }
    }

    if (OBF || SPLIT) {
        __syncthreads();
        constexpr int EST = 40;               // Eb stride (pad breaks 4-way)
        unsigned short* Eb = As + w * (16 * EST);
        const int erow = lane >> 3;           // 8 lanes per 32-col row
        const int ecol = (lane & 7) * 4;

        const int gnb   = n0 + wn;
        const int which = SPLIT ? (gnb >> 9) : 0;
        const int lnb   = SPLIT ? (gnb & 511) : gnb;
        const int ldo   = SPLIT ? 512 : N;
        unsigned short* oo = SPLIT
            ? ((which == 0) ? (unsigned short*)o0 : (which == 1) ? (unsigned short*)o1 : (unsigned short*)o2)
            : (unsigned short*)o0;
        const float* bb = SPLIT ? ((which == 0) ? b0 : (which == 1) ? b1 : b2) : b0;
        const float scale = (SPLIT && which == 0) ? 0.125f : 1.0f;

#pragma unroll
        for (int i = 0; i < 4; ++i) {
#pragma unroll
            for (int j = 0; j < 2; ++j) {
                const float bv = bb[lnb + j * 16 + l16];
#pragma unroll
                for (int r = 0; r < 4; ++r) {
                    float cv = acc[i][j][r] + bv;
                    if (ACT) cv = gelu_exact(cv);
                    if (SPLIT) cv *= scale;
                    Eb[(g16 * 4 + r) * EST + j * 16 + l16] = f2bf(cv);
                }
            }
            const int grow0 = m0 + wm + i * 16;
#pragma unroll
            for (int s = 0; s < 2; ++s) {
                ushort4 t4 = *(const ushort4*)&Eb[(s * 8 + erow) * EST + ecol];
                *(ushort4*)&oo[(size_t)(grow0 + s * 8 + erow) * ldo + lnb + ecol] = t4;
            }
        }
        return;
    }

    // fp32 out epilogue
#pragma unroll
    for (int i = 0; i < 4; ++i) {
        const int gmb = m0 + wm + i * 16 + g16 * 4;
#pragma unroll
        for (int j = 0; j < 2; ++j) {
            const int gn = n0 + wn + j * 16 + l16;
            const float bv = b0[gn];
#pragma unroll
            for (int r = 0; r < 4; ++r) {
                float cv = acc[i][j][r] + bv;
                if (ACT) cv = gelu_exact(cv);
                if (RES) cv += res[(size_t)(gmb + r) * 512 + gn];
                ((float*)o0)[(size_t)(gmb + r) * N + gn] = cv;
            }
        }
    }
}

// ---------------------------------------------------------------------------
// Fused prologue: ONE dispatch for all weight transposes + spikes convert.
// ---------------------------------------------------------------------------
__global__ __launch_bounds__(256) void prep_k(
    const float* __restrict__ spikes,
    const float* __restrict__ embed_w, const float* __restrict__ proj_w,
    const float* __restrict__ Wq, const float* __restrict__ Wk,
    const float* __restrict__ Wv, const float* __restrict__ Wo,
    const float* __restrict__ up_w, const float* __restrict__ down_w,
    unsigned short* __restrict__ spbf,
    unsigned short* __restrict__ embT, unsigned short* __restrict__ projT,
    unsigned short* __restrict__ qkvT, unsigned short* __restrict__ woT,
    unsigned short* __restrict__ upT, unsigned short* __restrict__ downT)
{
    const int idx = blockIdx.x;
    const int tid = threadIdx.x;

    if (idx >= 3120) {  // spikes fp32->bf16: 256 blocks x 4096 elems
        const int base = (idx - 3120) * 4096 + tid * 16;
#pragma unroll
        for (int s = 0; s < 4; ++s) {
            float4 v = *(const float4*)&spikes[base + s * 4];
            ushort4 o = {f2bf(v.x), f2bf(v.y), f2bf(v.z), f2bf(v.w)};
            *(ushort4*)&spbf[base + s * 4] = o;
        }
        return;
    }

    const float* src; unsigned short* dst; int R, Cc, t;
    if (idx < 16)      { src = embed_w; dst = embT;  R = C_; Cc = D_; t = idx; }
    else if (idx < 48) { src = proj_w;  dst = projT; R = D_; Cc = H_; t = idx - 16; }
    else if (idx < 816) {
        const int j = idx - 48;        // 0..767: Wq | Wk | Wv, 4 layers x 64 tiles
        const int wsel = j >> 8;
        const int l = (j & 255) >> 6;
        t = j & 63;
        src = ((wsel == 0) ? Wq : (wsel == 1) ? Wk : Wv) + (size_t)l * H_ * H_;
        dst = qkvT + (size_t)l * 3 * H_ * H_ + (size_t)wsel * H_ * H_;
        R = H_; Cc = H_;
    } else if (idx < 1072) {
        const int j = idx - 816; const int l = j >> 6; t = j & 63;
        src = Wo + (size_t)l * H_ * H_; dst = woT + (size_t)l * H_ * H_;
        R = H_; Cc = H_;
    } else if (idx < 2096) {
        const int j = idx - 1072; const int l = j >> 8; t = j & 255;
        src = up_w + (size_t)l * H_ * INTER_; dst = upT + (size_t)l * INTER_ * H_;
        R = H_; Cc = INTER_;
    } else {
        const int j = idx - 2096; const int l = j >> 8; t = j & 255;
        src = down_w + (size_t)l * INTER_ * H_; dst = downT + (size_t)l * H_ * INTER_;
        R = INTER_; Cc = H_;
    }
    const int ntx = Cc >> 6;
    const int c0 = (t % ntx) * 64, r0 = (t / ntx) * 64;

    __shared__ float tile[64][65];
    const int tr = tid >> 4, tc = (tid & 15) * 4;
#pragma unroll
    for (int i = 0; i < 4; ++i) {
        float4 v = *(const float4*)&src[(size_t)(r0 + tr + i * 16) * Cc + c0 + tc];
        tile[tr + i * 16][tc + 0] = v.x;
        tile[tr + i * 16][tc + 1] = v.y;
        tile[tr + i * 16][tc + 2] = v.z;
        tile[tr + i * 16][tc + 3] = v.w;
    }
    __syncthreads();
#pragma unroll
    for (int i = 0; i < 4; ++i) {
        const int n = tr + i * 16;
        ushort4 o;
        o.x = f2bf(tile[tc + 0][n]);
        o.y = f2bf(tile[tc + 1][n]);
        o.z = f2bf(tile[tc + 2][n]);
        o.w = f2bf(tile[tc + 3][n]);
        *(ushort4*)&dst[(size_t)(c0 + n) * R + r0 + tc] = o;
    }
}

// ---------------------------------------------------------------------------
// LayerNorm over H=512, bf16 output. INIT=1 additionally writes
// xb = x + db (fp32) -- the residual+bias init target for split-K atomics.
// ---------------------------------------------------------------------------
template<int INIT>
__global__ __launch_bounds__(256) void ln_k(
    const float* __restrict__ x, const float* __restrict__ g,
    const float* __restrict__ b, const float* __restrict__ db,
    unsigned short* __restrict__ out, float* __restrict__ xb)
{
    const int row = blockIdx.x;
    const int tid = threadIdx.x;
    const float* xr = x + (size_t)row * H_;

    float v0 = xr[tid];
    float v1 = xr[tid + 256];

    if (INIT) {
        xb[(size_t)row * H_ + tid]       = v0 + db[tid];
        xb[(size_t)row * H_ + tid + 256] = v1 + db[tid + 256];
    }

    float s = v0 + v1;
#pragma unroll
    for (int off = 32; off; off >>= 1) s += __shfl_xor(s, off);

    __shared__ float red[4];
    const int wave = tid >> 6;
    if ((tid & 63) == 0) red[wave] = s;
    __syncthreads();
    const float mean = (red[0] + red[1] + red[2] + red[3]) * (1.0f / (float)H_);

    const float d0 = v0 - mean, d1 = v1 - mean;
    float q = d0 * d0 + d1 * d1;
#pragma unroll
    for (int off = 32; off; off >>= 1) q += __shfl_xor(q, off);
    __syncthreads();
    if ((tid & 63) == 0) red[wave] = q;
    __syncthreads();
    const float var = (red[0] + red[1] + red[2] + red[3]) * (1.0f / (float)H_);
    const float rstd = rsqrtf(var + 1e-5f);

    out[(size_t)row * H_ + tid]       = f2bf(d0 * rstd * g[tid] + b[tid]);
    out[(size_t)row * H_ + tid + 256] = f2bf(d1 * rstd * g[tid + 256] + b[tid + 256]);
}

// ---------------------------------------------------------------------------
// MFMA banded attention with RoPE fused into Q/K staging. XCD-chunked blk
// swizzle: consecutive q-tiles (128/192 shared K/V window rows) co-reside
// per XCD for L2 reuse.
// ---------------------------------------------------------------------------
#define AWIN 192
#define AKS 72
#define AVS 200

__global__ __launch_bounds__(256) void attn_k(
    const unsigned short* __restrict__ q, const unsigned short* __restrict__ k,
    const unsigned short* __restrict__ v, const int* __restrict__ smask,
    const int* __restrict__ ts, unsigned short* __restrict__ o)
{
    __shared__ unsigned short Qs[64 * AKS];
    __shared__ unsigned short Ks[AWIN * AKS];   // reused as Pb after S-pass
    __shared__ unsigned short Vt[64 * AVS];
    unsigned short* const Pb = Ks;              // 64*AVS = 12800 <= 13824

    int blk = blockIdx.x;
    blk = (blk & 7) * ((int)gridDim.x >> 3) + (blk >> 3);
    const int qt = blk & 15;
    const int h  = (blk >> 4) & 7;
    const int b  = blk >> 7;
    const int tid  = threadIdx.x;
    const int lane = tid & 63;
    const int w    = tid >> 6;
    const int l16  = lane & 15;
    const int g16  = lane >> 4;

    const int qlo = qt * 64;
    const int klo = (qlo >= CB_) ? (qlo - CB_) : 0;
    const int tb  = b * 1024;

    // ---- stage Q with RoPE (q pre-scaled 0.125 in QKV epilogue) ----
    {
        const unsigned short* gq = q + ((size_t)(tb + qlo)) * 512 + h * 64;
        for (int c = tid; c < 64 * 8; c += 256) {
            const int row = c >> 3, c4 = (c & 7) * 4;   // d = c4..c4+3 in [0,32)
            ushort4 lo = *(const ushort4*)&gq[(size_t)row * 512 + c4];
            ushort4 hi = *(const ushort4*)&gq[(size_t)row * 512 + c4 + 32];
            const float tstamp = (float)ts[tb + qlo + row];
            ushort4 olo, ohi;
#pragma unroll
            for (int j2 = 0; j2 < 4; ++j2) {
                const float freq = __expf(-0.2878231366242558f * (float)(c4 + j2));
                const float ang = tstamp * freq;
                const float cc = __cosf(ang), ss = __sinf(ang);
                const float v1 = bf2f(((const unsigned short*)&lo)[j2]);
                const float v2 = bf2f(((const unsigned short*)&hi)[j2]);
                ((unsigned short*)&olo)[j2] = f2bf(v1 * cc - v2 * ss);
                ((unsigned short*)&ohi)[j2] = f2bf(v2 * cc + v1 * ss);
            }
            *(ushort4*)&Qs[row * AKS + c4]      = olo;
            *(ushort4*)&Qs[row * AKS + c4 + 32] = ohi;
        }
    }
    // ---- stage K with RoPE ----
    {
        const unsigned short* gk = k + ((size_t)(tb + klo)) * 512 + h * 64;
        for (int c = tid; c < AWIN * 8; c += 256) {
            const int row = c >> 3, c4 = (c & 7) * 4;
            ushort4 lo = *(const ushort4*)&gk[(size_t)row * 512 + c4];
            ushort4 hi = *(const ushort4*)&gk[(size_t)row * 512 + c4 + 32];
            const float tstamp = (float)ts[tb + klo + row];
            ushort4 olo, ohi;
#pragma unroll
            for (int j2 = 0; j2 < 4; ++j2) {
                const float freq = __expf(-0.2878231366242558f * (float)(c4 + j2));
                const float ang = tstamp * freq;
                const float cc = __cosf(ang), ss = __sinf(ang);
                const float v1 = bf2f(((const unsigned short*)&lo)[j2]);
                const float v2 = bf2f(((const unsigned short*)&hi)[j2]);
                ((unsigned short*)&olo)[j2] = f2bf(v1 * cc - v2 * ss);
                ((unsigned short*)&ohi)[j2] = f2bf(v2 * cc + v1 * ss);
            }
            *(ushort4*)&Ks[row * AKS + c4]      = olo;
            *(ushort4*)&Ks[row * AKS + c4 + 32] = ohi;
        }
    }
    // ---- stage V (transposed into LDS) ----
    {
        const unsigned short* gv = v + ((size_t)(tb + klo)) * 512 + h * 64;
        for (int c = tid; c < AWIN * 16; c += 256) {
            const int row = c >> 4, c4 = (c & 15) * 4;
            ushort4 vv = *(const ushort4*)&gv[(size_t)row * 512 + c4];
            Vt[(c4 + 0) * AVS + row] = vv.x;
            Vt[(c4 + 1) * AVS + row] = vv.y;
            Vt[(c4 + 2) * AVS + row] = vv.z;
            Vt[(c4 + 3) * AVS + row] = vv.w;
        }
    }
    __syncthreads();

    // ---- S = Q @ K^T ----
    f32x4 accs[12];
    {
        const bf16x8 a0 = *(const bf16x8*)&Qs[(w * 16 + l16) * AKS + g16 * 8];
        const bf16x8 a1 = *(const bf16x8*)&Qs[(w * 16 + l16) * AKS + 32 + g16 * 8];
#pragma unroll
        for (int t = 0; t < 12; ++t) {
            const bf16x8 b0 = *(const bf16x8*)&Ks[(t * 16 + l16) * AKS + g16 * 8];
            const bf16x8 b1 = *(const bf16x8*)&Ks[(t * 16 + l16) * AKS + 32 + g16 * 8];
            f32x4 c = {};
            c = __builtin_amdgcn_mfma_f32_16x16x32_bf16(a0, b0, c, 0, 0, 0);
            c = __builtin_amdgcn_mfma_f32_16x16x32_bf16(a1, b1, c, 0, 0, 0);
            accs[t] = c;
        }
    }

    // ---- softmax in registers ----
    bool mk[12];
    int  jj[12];
#pragma unroll
    for (int t = 0; t < 12; ++t) {
        jj[t] = klo + t * 16 + l16;
        mk[t] = smask[tb + jj[t]] > 0;
    }

    float rs[4];
#pragma unroll
    for (int r = 0; r < 4; ++r) {
        const int i = qlo + 16 * w + g16 * 4 + r;
        float mx = -1e30f;
#pragma unroll
        for (int t = 0; t < 12; ++t) {
            const bool val = mk[t] && (jj[t] >= i - CB_) && (jj[t] <= i);
            mx = fmaxf(mx, val ? accs[t][r] : -1e30f);
        }
        mx = fmaxf(mx, __shfl_xor(mx, 1));
        mx = fmaxf(mx, __shfl_xor(mx, 2));
        mx = fmaxf(mx, __shfl_xor(mx, 4));
        mx = fmaxf(mx, __shfl_xor(mx, 8));
        float sum = 0.0f;
#pragma unroll
        for (int t = 0; t < 12; ++t) {
            const bool val = mk[t] && (jj[t] >= i - CB_) && (jj[t] <= i);
            const float p = val ? __expf(accs[t][r] - mx) : 0.0f;
            accs[t][r] = p;
            sum += p;
        }
        sum += __shfl_xor(sum, 1);
        sum += __shfl_xor(sum, 2);
        sum += __shfl_xor(sum, 4);
        sum += __shfl_xor(sum, 8);
        rs[r] = 1.0f / sum;
    }

    // Ks dead from here; Pb aliases it.
    __syncthreads();

    // ---- P -> LDS ----
#pragma unroll
    for (int t = 0; t < 12; ++t)
#pragma unroll
        for (int r = 0; r < 4; ++r)
            Pb[(16 * w + g16 * 4 + r) * AVS + t * 16 + l16] = f2bf(accs[t][r]);

    // ---- O = P @ V ----
    f32x4 acco[4];
#pragma unroll
    for (int nt = 0; nt < 4; ++nt) {
        f32x4 c = {};
#pragma unroll
        for (int ks = 0; ks < 6; ++ks) {
            const bf16x8 a = *(const bf16x8*)&Pb[(16 * w + l16) * AVS + ks * 32 + g16 * 8];
            const bf16x8 bb = *(const bf16x8*)&Vt[(nt * 16 + l16) * AVS + ks * 32 + g16 * 8];
            c = __builtin_amdgcn_mfma_f32_16x16x32_bf16(a, bb, c, 0, 0, 0);
        }
        acco[nt] = c;
    }

    // ---- stage O into Pb, vector store ----
    __syncthreads();
#pragma unroll
    for (int nt = 0; nt < 4; ++nt)
#pragma unroll
        for (int r = 0; r < 4; ++r)
            Pb[(16 * w + g16 * 4 + r) * AVS + nt * 16 + l16] = f2bf(acco[nt][r] * rs[r]);

    const int row16 = lane >> 2, cg = lane & 3;
    const int grow = tb + qlo + 16 * w + row16;
#pragma unroll
    for (int s = 0; s < 4; ++s) {
        ushort4 t4 = *(const ushort4*)&Pb[(16 * w + row16) * AVS + s * 16 + cg * 4];
        *(ushort4*)&o[(size_t)grow * 512 + h * 64 + s * 16 + cg * 4] = t4;
    }
}

// ---------------------------------------------------------------------------
extern "C" void kernel_launch(void* const* d_in, const int* in_sizes, int n_in,
                              void* d_out, int out_size, void* d_ws, size_t ws_size,
                              hipStream_t stream)
{
    const float* spikes  = (const float*)d_in[0];
    const int*   smask   = (const int*)d_in[1];
    const int*   ts      = (const int*)d_in[2];
    const float* embed_w = (const float*)d_in[3];
    const float* embed_b = (const float*)d_in[4];
    const float* proj_w  = (const float*)d_in[5];
    const float* proj_b  = (const float*)d_in[6];
    const float* ln1_g   = (const float*)d_in[7];
    const float* ln1_b   = (const float*)d_in[8];
    const float* Wq      = (const float*)d_in[9];
    const float* bq      = (const float*)d_in[10];
    const float* Wk      = (const float*)d_in[11];
    const float* bk      = (const float*)d_in[12];
    const float* Wv      = (const float*)d_in[13];
    const float* bv      = (const float*)d_in[14];
    const float* Wo      = (const float*)d_in[15];
    const float* bo      = (const float*)d_in[16];
    const float* ln2_g   = (const float*)d_in[17];
    const float* ln2_b   = (const float*)d_in[18];
    const float* up_w    = (const float*)d_in[19];
    const float* up_b    = (const float*)d_in[20];
    const float* down_w  = (const float*)d_in[21];
    const float* down_b  = (const float*)d_in[22];

    const int M = B_ * T_;  // 4096

    char* p = (char*)d_ws;
    float* x  = (float*)p;                      p += (size_t)M * H_ * 4;
    float* x2 = (float*)p;                      p += (size_t)M * H_ * 4;
    unsigned short* qb  = (unsigned short*)p;   p += (size_t)M * H_ * 2;
    unsigned short* kb  = (unsigned short*)p;   p += (size_t)M * H_ * 2;
    unsigned short* vb  = (unsigned short*)p;   p += (size_t)M * H_ * 2;
    unsigned short* hbf = (unsigned short*)p;   p += (size_t)M * H_ * 2;
    unsigned short* obf = (unsigned short*)p;   p += (size_t)M * H_ * 2;
    unsigned short* ibf = (unsigned short*)p;   p += (size_t)M * INTER_ * 2;
    unsigned short* tbf = (unsigned short*)p;   p += (size_t)M * D_ * 2;
    unsigned short* spbf  = (unsigned short*)p; p += (size_t)M * C_ * 2;
    unsigned short* embT  = (unsigned short*)p; p += (size_t)D_ * C_ * 2;
    unsigned short* projT = (unsigned short*)p; p += (size_t)H_ * D_ * 2;
    unsigned short* qkvT  = (unsigned short*)p; p += (size_t)L_ * 3 * H_ * H_ * 2;
    unsigned short* woT   = (unsigned short*)p; p += (size_t)L_ * H_ * H_ * 2;
    unsigned short* upT   = (unsigned short*)p; p += (size_t)L_ * INTER_ * H_ * 2;
    unsigned short* downT = (unsigned short*)p; p += (size_t)L_ * H_ * INTER_ * 2;

    // ---- fused prologue: all weight transposes + spikes convert, 1 dispatch
    prep_k<<<3376, 256, 0, stream>>>(
        spikes, embed_w, proj_w, Wq, Wk, Wv, Wo, up_w, down_w,
        spbf, embT, projT, qkvT, woT, upT, downT);

    // ---- embedding ----
    mm64_k<1, 0, 1, 0, 0><<<dim3(D_ / 64, M / 64), 256, 0, stream>>>(
        spbf, embT, embed_b, nullptr, nullptr, nullptr,
        tbf, nullptr, nullptr, M, D_, C_);
    mm64_k<0, 0, 0, 0, 0><<<dim3(H_ / 64, M / 64), 256, 0, stream>>>(
        tbf, projT, proj_b, nullptr, nullptr, nullptr,
        x, nullptr, nullptr, M, H_, D_);

    float* cur = x;
    float* alt = x2;

    for (int l = 0; l < L_; ++l) {
        const unsigned short* qkvT_l = qkvT + (size_t)l * 3 * H_ * H_;
        const unsigned short* woT_l  = woT  + (size_t)l * H_ * H_;
        const unsigned short* upT_l  = upT  + (size_t)l * INTER_ * H_;
        const unsigned short* dnT_l  = downT + (size_t)l * H_ * INTER_;

        ln_k<0><<<M, 256, 0, stream>>>(cur, ln1_g + l * H_, ln1_b + l * H_,
                                       nullptr, hbf, nullptr);

        // fused QKV + bias (+0.125 q scale) -> qb, kb, vb (bf16 [M,512])
        // 128x64 tile: grid 24x32 = 768 blocks = 3 blocks/CU
        mm128_k<0, 0, 1, 1><<<dim3((3 * H_) / 64, M / 128), 256, 0, stream>>>(
            hbf, qkvT_l, bq + l * H_, bk + l * H_, bv + l * H_, nullptr,
            qb, kb, vb, M, 3 * H_, H_);

        // attention (RoPE fused into staging)
        attn_k<<<B_ * NH_ * (T_ / 64), 256, 0, stream>>>(qb, kb, vb, smask, ts, obf);

        // x = x + obuf @ Wo + bo  (64x64: grid 512 = 2 blocks/CU)
        mm64_k<0, 1, 0, 0, 0><<<dim3(H_ / 64, M / 64), 256, 0, stream>>>(
            obf, woT_l, bo + l * H_, nullptr, nullptr, cur,
            cur, nullptr, nullptr, M, H_, H_);

        // ln2 + init xd = x + down_b (split-K atomic target)
        float* xd = (l == L_ - 1) ? (float*)d_out : alt;
        ln_k<1><<<M, 256, 0, stream>>>(cur, ln2_g + l * H_, ln2_b + l * H_,
                                       down_b + l * H_, hbf, xd);

        // inter = gelu(h @ up_w + b)  (128x64: grid 32x32 = 1024 blocks)
        mm128_k<1, 0, 1, 0><<<dim3(INTER_ / 64, M / 128), 256, 0, stream>>>(
            hbf, upT_l, up_b + l * INTER_, nullptr, nullptr, nullptr,
            ibf, nullptr, nullptr, M, INTER_, H_);

        // xd += inter @ down_w  (split-K=4: grid (8,64,4) = 2048 blocks,
        // 8 blocks/CU; fp32 atomic accumulate into pre-initialized xd)
        mm64_k<0, 0, 0, 0, 1><<<dim3(H_ / 64, M / 64, 4), 256, 0, stream>>>(
            ibf, dnT_l, nullptr, nullptr, nullptr, nullptr,
            xd, nullptr, nullptr, M, H_, INTER_);

        alt = cur;
        cur = xd;
    }
}

// Round 4
// 535.312 us; speedup vs baseline: 1.0498x; 1.0498x over previous
//
#include <hip/hip_runtime.h>
#include <math.h>

// Problem dims (fixed)
#define B_ 4
#define T_ 1024
#define C_ 256
#define D_ 256
#define H_ 512
#define NH_ 8
#define HD_ 64
#define INTER_ 2048
#define L_ 4
#define CB_ 128   // context_backward; context_forward = 0

typedef short bf16x8 __attribute__((ext_vector_type(8)));
typedef float f32x4 __attribute__((ext_vector_type(4)));

__device__ __forceinline__ float gelu_exact(float x) {
    return 0.5f * x * (1.0f + erff(x * 0.70710678118654752f));
}

// fp32 -> bf16 round-to-nearest-even
__device__ __forceinline__ unsigned short f2bf(float f) {
    unsigned u = __float_as_uint(f);
    u += 0x7fffu + ((u >> 16) & 1u);
    return (unsigned short)(u >> 16);
}
__device__ __forceinline__ float bf2f(unsigned short h) {
    return __uint_as_float((unsigned)h << 16);
}

// XCD-chunked bijective block swizzle (T1). Requires nwg % 8 == 0.
__device__ __forceinline__ void xcd_swz(int& bx, int& by) {
    const int gx  = gridDim.x;
    const int nwg = gx * gridDim.y;
    int bid = blockIdx.y * gx + blockIdx.x;
    bid = (bid & 7) * (nwg >> 3) + (bid >> 3);
    bx = bid % gx;
    by = bid / gx;
}

// ---------------------------------------------------------------------------
// bf16 MFMA GEMM, 64x64 tile, BK=64, XOR-swizzled LDS, DOUBLE-BUFFERED
// single-barrier prefetch pipeline (T3 minimal 2-phase): per K-step,
// barrier (implicit vmcnt0 drains prev prefetch) -> issue next tile's
// global_load_lds into buf^1 -> compute buf[cur] (MFMA overlaps DMA).
// R3 lesson: split-K atomics cost more than the latency they saved; this
// hides the same latency with zero extra traffic.
// ---------------------------------------------------------------------------
template<int ACT, int RES, int OBF, int SPLIT>
__global__ __launch_bounds__(256) void mm64_k(
    const unsigned short* __restrict__ A, const unsigned short* __restrict__ BT,
    const float* __restrict__ b0, const float* __restrict__ b1,
    const float* __restrict__ b2,
    const float* res,
    void* o0, void* o1, void* o2,
    const int M, const int N, const int K)
{
    __shared__ unsigned short As[2][64 * 64];
    __shared__ unsigned short Bs[2][64 * 64];

    int bx, by; xcd_swz(bx, by);

    const int tid  = threadIdx.x;
    const int lane = tid & 63;
    const int w    = tid >> 6;
    const int m0   = by * 64;
    const int n0   = bx * 64;
    const int wm   = (w >> 1) * 32;
    const int wn   = (w & 1) * 32;
    const int l16  = lane & 15;
    const int g16  = lane >> 4;

    f32x4 acc[2][2] = {};

    const unsigned short* Abase = A  + (size_t)m0 * K;
    const unsigned short* Bbase = BT + (size_t)n0 * K;

    // staging chunks: c0 = w*64+lane (rows 8w..8w+7), c1 = c0+256 (rows 32..63)
    const int c0 = (w << 6) + lane;
    const int c1 = c0 + 256;
    const int r0c = c0 >> 3, gk0 = (c0 & 7) ^ (r0c & 7);
    const int r1c = c1 >> 3, gk1 = (c1 & 7) ^ (r1c & 7);

#define STAGE64(buf, kk0) do {                                                                        \
    __builtin_amdgcn_global_load_lds(                                                                 \
        (const __attribute__((address_space(1))) unsigned*)(Abase + (size_t)r0c * K + (kk0) + gk0 * 8), \
        (__attribute__((address_space(3))) unsigned*)(As[buf] + (size_t)(w << 6) * 8), 16, 0, 0);     \
    __builtin_amdgcn_global_load_lds(                                                                 \
        (const __attribute__((address_space(1))) unsigned*)(Abase + (size_t)r1c * K + (kk0) + gk1 * 8), \
        (__attribute__((address_space(3))) unsigned*)(As[buf] + (size_t)(256 + (w << 6)) * 8), 16, 0, 0); \
    __builtin_amdgcn_global_load_lds(                                                                 \
        (const __attribute__((address_space(1))) unsigned*)(Bbase + (size_t)r0c * K + (kk0) + gk0 * 8), \
        (__attribute__((address_space(3))) unsigned*)(Bs[buf] + (size_t)(w << 6) * 8), 16, 0, 0);     \
    __builtin_amdgcn_global_load_lds(                                                                 \
        (const __attribute__((address_space(1))) unsigned*)(Bbase + (size_t)r1c * K + (kk0) + gk1 * 8), \
        (__attribute__((address_space(3))) unsigned*)(Bs[buf] + (size_t)(256 + (w << 6)) * 8), 16, 0, 0); \
} while (0)

    STAGE64(0, 0);
    int cur = 0;
    for (int k0 = 0; k0 < K; k0 += 64) {
        __syncthreads();   // implicit vmcnt(0): tile k0's DMA has landed
        if (k0 + 64 < K) STAGE64(cur ^ 1, k0 + 64);   // prefetch overlaps compute

#pragma unroll
        for (int kk = 0; kk < 2; ++kk) {
            const int kf = kk * 4 + g16;            // global k-group 0..7
            const int sw = (kf ^ (l16 & 7)) * 8;    // swizzled ushort offset
            bf16x8 a[2], b[2];
#pragma unroll
            for (int t = 0; t < 2; ++t)
                a[t] = *(const bf16x8*)&As[cur][(wm + t * 16 + l16) * 64 + sw];
#pragma unroll
            for (int t = 0; t < 2; ++t)
                b[t] = *(const bf16x8*)&Bs[cur][(wn + t * 16 + l16) * 64 + sw];
#pragma unroll
            for (int i = 0; i < 2; ++i)
#pragma unroll
                for (int j = 0; j < 2; ++j)
                    acc[i][j] = __builtin_amdgcn_mfma_f32_16x16x32_bf16(a[i], b[j], acc[i][j], 0, 0, 0);
        }
        cur ^= 1;
    }
#undef STAGE64

    if (OBF || SPLIT) {
        __syncthreads();
        unsigned short* Eb = ((w < 2) ? As[0] : Bs[0]) + (w & 1) * 1024;
        const int row16 = lane >> 2;
        const int cg    = lane & 3;

        const int gnb   = n0 + wn;
        const int which = SPLIT ? (gnb >> 9) : 0;
        const int lnb   = SPLIT ? (gnb & 511) : gnb;
        const int ldo   = SPLIT ? 512 : N;
        unsigned short* oo = SPLIT
            ? ((which == 0) ? (unsigned short*)o0 : (which == 1) ? (unsigned short*)o1 : (unsigned short*)o2)
            : (unsigned short*)o0;
        const float* bb = SPLIT ? ((which == 0) ? b0 : (which == 1) ? b1 : b2) : b0;
        const float scale = (SPLIT && which == 0) ? 0.125f : 1.0f;

#pragma unroll
        for (int i = 0; i < 2; ++i) {
#pragma unroll
            for (int j = 0; j < 2; ++j) {
                const float bv = bb[lnb + j * 16 + l16];
#pragma unroll
                for (int r = 0; r < 4; ++r) {
                    float cv = acc[i][j][r] + bv;
                    if (ACT) cv = gelu_exact(cv);
                    if (SPLIT) cv *= scale;
                    Eb[(g16 * 4 + r) * 40 + j * 16 + l16] = f2bf(cv);
                }
            }
            const int grow0 = m0 + wm + i * 16 + row16;
#pragma unroll
            for (int s = 0; s < 2; ++s) {
                ushort4 t4 = *(const ushort4*)&Eb[row16 * 40 + s * 16 + cg * 4];
                *(ushort4*)&oo[(size_t)grow0 * ldo + lnb + s * 16 + cg * 4] = t4;
            }
        }
        return;
    }

    // fp32 out epilogue (scalar 4B stores = full 64B runs per 16 lanes)
#pragma unroll
    for (int i = 0; i < 2; ++i) {
        const int gmb = m0 + wm + i * 16 + g16 * 4;
#pragma unroll
        for (int j = 0; j < 2; ++j) {
            const int gn = n0 + wn + j * 16 + l16;
            const float bv = b0[gn];
#pragma unroll
            for (int r = 0; r < 4; ++r) {
                float cv = acc[i][j][r] + bv;
                if (ACT) cv = gelu_exact(cv);
                if (RES) cv += res[(size_t)(gmb + r) * 512 + gn];
                ((float*)o0)[(size_t)(gmb + r) * N + gn] = cv;
            }
        }
    }
}

// ---------------------------------------------------------------------------
// bf16 MFMA GEMM, 128x64 tile, BK=64, double-buffered prefetch (as above).
// For wide-N GEMMs (QKV N=1536 grid 768, up N=2048 grid 1024 -> 3-4
// blocks/CU). LDS 48 KB -> exactly 3 blocks/CU.
// ---------------------------------------------------------------------------
template<int ACT, int RES, int OBF, int SPLIT>
__global__ __launch_bounds__(256) void mm128_k(
    const unsigned short* __restrict__ A, const unsigned short* __restrict__ BT,
    const float* __restrict__ b0, const float* __restrict__ b1,
    const float* __restrict__ b2,
    const float* res,
    void* o0, void* o1, void* o2,
    const int M, const int N, const int K)
{
    __shared__ unsigned short As[2][128 * 64];
    __shared__ unsigned short Bs[2][64 * 64];

    int bx, by; xcd_swz(bx, by);

    const int tid  = threadIdx.x;
    const int lane = tid & 63;
    const int w    = tid >> 6;
    const int m0   = by * 128;
    const int n0   = bx * 64;
    const int wm   = (w >> 1) * 64;       // 0 or 64
    const int wn   = (w & 1) * 32;        // 0 or 32
    const int l16  = lane & 15;
    const int g16  = lane >> 4;

    f32x4 acc[4][2] = {};

    const unsigned short* Abase = A  + (size_t)m0 * K;
    const unsigned short* Bbase = BT + (size_t)n0 * K;

#define STAGE128(buf, kk0) do {                                                                           \
    _Pragma("unroll")                                                                                     \
    for (int it = 0; it < 4; ++it) {                                                                      \
        const int c = it * 256 + tid;                                                                     \
        const int rc = c >> 3, gk = (c & 7) ^ (rc & 7);                                                   \
        __builtin_amdgcn_global_load_lds(                                                                 \
            (const __attribute__((address_space(1))) unsigned*)(Abase + (size_t)rc * K + (kk0) + gk * 8), \
            (__attribute__((address_space(3))) unsigned*)(As[buf] + (size_t)(it * 256 + (w << 6)) * 8), 16, 0, 0); \
    }                                                                                                     \
    _Pragma("unroll")                                                                                     \
    for (int it = 0; it < 2; ++it) {                                                                      \
        const int c = it * 256 + tid;                                                                     \
        const int rc = c >> 3, gk = (c & 7) ^ (rc & 7);                                                   \
        __builtin_amdgcn_global_load_lds(                                                                 \
            (const __attribute__((address_space(1))) unsigned*)(Bbase + (size_t)rc * K + (kk0) + gk * 8), \
            (__attribute__((address_space(3))) unsigned*)(Bs[buf] + (size_t)(it * 256 + (w << 6)) * 8), 16, 0, 0); \
    }                                                                                                     \
} while (0)

    STAGE128(0, 0);
    int cur = 0;
    for (int k0 = 0; k0 < K; k0 += 64) {
        __syncthreads();   // implicit vmcnt(0): tile k0's DMA has landed
        if (k0 + 64 < K) STAGE128(cur ^ 1, k0 + 64);

#pragma unroll
        for (int kk = 0; kk < 2; ++kk) {
            const int kf = kk * 4 + g16;            // global k-group 0..7
            const int sw = (kf ^ (l16 & 7)) * 8;    // swizzled ushort offset
            bf16x8 a[4], b[2];
#pragma unroll
            for (int t = 0; t < 4; ++t)
                a[t] = *(const bf16x8*)&As[cur][(wm + t * 16 + l16) * 64 + sw];
#pragma unroll
            for (int t = 0; t < 2; ++t)
                b[t] = *(const bf16x8*)&Bs[cur][(wn + t * 16 + l16) * 64 + sw];
#pragma unroll
            for (int i = 0; i < 4; ++i)
#pragma unroll
                for (int j = 0; j < 2; ++j)
                    acc[i][j] = __builtin_amdgcn_mfma_f32_16x16x32_bf16(a[i], b[j], acc[i][j], 0, 0, 0);
        }
        cur ^= 1;
    }
#undef STAGE128

    if (OBF || SPLIT) {
        __syncthreads();
        constexpr int EST = 40;               // Eb stride (pad breaks 4-way)
        unsigned short* Eb = As[0] + w * (16 * EST);
        const int erow = lane >> 3;           // 8 lanes per 32-col row
        const int ecol = (lane & 7) * 4;

        const int gnb   = n0 + wn;
        const int which = SPLIT ? (gnb >> 9) : 0;
        const int lnb   = SPLIT ? (gnb & 511) : gnb;
        const int ldo   = SPLIT ? 512 : N;
        unsigned short* oo = SPLIT
            ? ((which == 0) ? (unsigned short*)o0 : (which == 1) ? (unsigned short*)o1 : (unsigned short*)o2)
            : (unsigned short*)o0;
        const float* bb = SPLIT ? ((which == 0) ? b0 : (which == 1) ? b1 : b2) : b0;
        const float scale = (SPLIT && which == 0) ? 0.125f : 1.0f;

#pragma unroll
        for (int i = 0; i < 4; ++i) {
#pragma unroll
            for (int j = 0; j < 2; ++j) {
                const float bv = bb[lnb + j * 16 + l16];
#pragma unroll
                for (int r = 0; r < 4; ++r) {
                    float cv = acc[i][j][r] + bv;
                    if (ACT) cv = gelu_exact(cv);
                    if (SPLIT) cv *= scale;
                    Eb[(g16 * 4 + r) * EST + j * 16 + l16] = f2bf(cv);
                }
            }
            const int grow0 = m0 + wm + i * 16;
#pragma unroll
            for (int s = 0; s < 2; ++s) {
                ushort4 t4 = *(const ushort4*)&Eb[(s * 8 + erow) * EST + ecol];
                *(ushort4*)&oo[(size_t)(grow0 + s * 8 + erow) * ldo + lnb + ecol] = t4;
            }
        }
        return;
    }

    // fp32 out epilogue
#pragma unroll
    for (int i = 0; i < 4; ++i) {
        const int gmb = m0 + wm + i * 16 + g16 * 4;
#pragma unroll
        for (int j = 0; j < 2; ++j) {
            const int gn = n0 + wn + j * 16 + l16;
            const float bv = b0[gn];
#pragma unroll
            for (int r = 0; r < 4; ++r) {
                float cv = acc[i][j][r] + bv;
                if (ACT) cv = gelu_exact(cv);
                if (RES) cv += res[(size_t)(gmb + r) * 512 + gn];
                ((float*)o0)[(size_t)(gmb + r) * N + gn] = cv;
            }
        }
    }
}

// ---------------------------------------------------------------------------
// Fused prologue: ONE dispatch for all weight transposes + spikes convert.
// ---------------------------------------------------------------------------
__global__ __launch_bounds__(256) void prep_k(
    const float* __restrict__ spikes,
    const float* __restrict__ embed_w, const float* __restrict__ proj_w,
    const float* __restrict__ Wq, const float* __restrict__ Wk,
    const float* __restrict__ Wv, const float* __restrict__ Wo,
    const float* __restrict__ up_w, const float* __restrict__ down_w,
    unsigned short* __restrict__ spbf,
    unsigned short* __restrict__ embT, unsigned short* __restrict__ projT,
    unsigned short* __restrict__ qkvT, unsigned short* __restrict__ woT,
    unsigned short* __restrict__ upT, unsigned short* __restrict__ downT)
{
    const int idx = blockIdx.x;
    const int tid = threadIdx.x;

    if (idx >= 3120) {  // spikes fp32->bf16: 256 blocks x 4096 elems
        const int base = (idx - 3120) * 4096 + tid * 16;
#pragma unroll
        for (int s = 0; s < 4; ++s) {
            float4 v = *(const float4*)&spikes[base + s * 4];
            ushort4 o = {f2bf(v.x), f2bf(v.y), f2bf(v.z), f2bf(v.w)};
            *(ushort4*)&spbf[base + s * 4] = o;
        }
        return;
    }

    const float* src; unsigned short* dst; int R, Cc, t;
    if (idx < 16)      { src = embed_w; dst = embT;  R = C_; Cc = D_; t = idx; }
    else if (idx < 48) { src = proj_w;  dst = projT; R = D_; Cc = H_; t = idx - 16; }
    else if (idx < 816) {
        const int j = idx - 48;        // 0..767: Wq | Wk | Wv, 4 layers x 64 tiles
        const int wsel = j >> 8;
        const int l = (j & 255) >> 6;
        t = j & 63;
        src = ((wsel == 0) ? Wq : (wsel == 1) ? Wk : Wv) + (size_t)l * H_ * H_;
        dst = qkvT + (size_t)l * 3 * H_ * H_ + (size_t)wsel * H_ * H_;
        R = H_; Cc = H_;
    } else if (idx < 1072) {
        const int j = idx - 816; const int l = j >> 6; t = j & 63;
        src = Wo + (size_t)l * H_ * H_; dst = woT + (size_t)l * H_ * H_;
        R = H_; Cc = H_;
    } else if (idx < 2096) {
        const int j = idx - 1072; const int l = j >> 8; t = j & 255;
        src = up_w + (size_t)l * H_ * INTER_; dst = upT + (size_t)l * INTER_ * H_;
        R = H_; Cc = INTER_;
    } else {
        const int j = idx - 2096; const int l = j >> 8; t = j & 255;
        src = down_w + (size_t)l * INTER_ * H_; dst = downT + (size_t)l * H_ * INTER_;
        R = INTER_; Cc = H_;
    }
    const int ntx = Cc >> 6;
    const int c0 = (t % ntx) * 64, r0 = (t / ntx) * 64;

    __shared__ float tile[64][65];
    const int tr = tid >> 4, tc = (tid & 15) * 4;
#pragma unroll
    for (int i = 0; i < 4; ++i) {
        float4 v = *(const float4*)&src[(size_t)(r0 + tr + i * 16) * Cc + c0 + tc];
        tile[tr + i * 16][tc + 0] = v.x;
        tile[tr + i * 16][tc + 1] = v.y;
        tile[tr + i * 16][tc + 2] = v.z;
        tile[tr + i * 16][tc + 3] = v.w;
    }
    __syncthreads();
#pragma unroll
    for (int i = 0; i < 4; ++i) {
        const int n = tr + i * 16;
        ushort4 o;
        o.x = f2bf(tile[tc + 0][n]);
        o.y = f2bf(tile[tc + 1][n]);
        o.z = f2bf(tile[tc + 2][n]);
        o.w = f2bf(tile[tc + 3][n]);
        *(ushort4*)&dst[(size_t)(c0 + n) * R + r0 + tc] = o;
    }
}

// ---------------------------------------------------------------------------
// LayerNorm over H=512, bf16 output.
// ---------------------------------------------------------------------------
__global__ __launch_bounds__(256) void ln_k(
    const float* __restrict__ x, const float* __restrict__ g,
    const float* __restrict__ b, unsigned short* __restrict__ out)
{
    const int row = blockIdx.x;
    const int tid = threadIdx.x;
    const float* xr = x + (size_t)row * H_;

    float v0 = xr[tid];
    float v1 = xr[tid + 256];

    float s = v0 + v1;
#pragma unroll
    for (int off = 32; off; off >>= 1) s += __shfl_xor(s, off);

    __shared__ float red[4];
    const int wave = tid >> 6;
    if ((tid & 63) == 0) red[wave] = s;
    __syncthreads();
    const float mean = (red[0] + red[1] + red[2] + red[3]) * (1.0f / (float)H_);

    const float d0 = v0 - mean, d1 = v1 - mean;
    float q = d0 * d0 + d1 * d1;
#pragma unroll
    for (int off = 32; off; off >>= 1) q += __shfl_xor(q, off);
    __syncthreads();
    if ((tid & 63) == 0) red[wave] = q;
    __syncthreads();
    const float var = (red[0] + red[1] + red[2] + red[3]) * (1.0f / (float)H_);
    const float rstd = rsqrtf(var + 1e-5f);

    out[(size_t)row * H_ + tid]       = f2bf(d0 * rstd * g[tid] + b[tid]);
    out[(size_t)row * H_ + tid + 256] = f2bf(d1 * rstd * g[tid + 256] + b[tid + 256]);
}

// ---------------------------------------------------------------------------
// MFMA banded attention with RoPE fused into Q/K staging.
// ---------------------------------------------------------------------------
#define AWIN 192
#define AKS 72
#define AVS 200

__global__ __launch_bounds__(256) void attn_k(
    const unsigned short* __restrict__ q, const unsigned short* __restrict__ k,
    const unsigned short* __restrict__ v, const int* __restrict__ smask,
    const int* __restrict__ ts, unsigned short* __restrict__ o)
{
    __shared__ unsigned short Qs[64 * AKS];
    __shared__ unsigned short Ks[AWIN * AKS];   // reused as Pb after S-pass
    __shared__ unsigned short Vt[64 * AVS];
    unsigned short* const Pb = Ks;              // 64*AVS = 12800 <= 13824

    const int blk = blockIdx.x;
    const int qt = blk & 15;
    const int h  = (blk >> 4) & 7;
    const int b  = blk >> 7;
    const int tid  = threadIdx.x;
    const int lane = tid & 63;
    const int w    = tid >> 6;
    const int l16  = lane & 15;
    const int g16  = lane >> 4;

    const int qlo = qt * 64;
    const int klo = (qlo >= CB_) ? (qlo - CB_) : 0;
    const int tb  = b * 1024;

    // ---- stage Q with RoPE (q pre-scaled 0.125 in QKV epilogue) ----
    {
        const unsigned short* gq = q + ((size_t)(tb + qlo)) * 512 + h * 64;
        for (int c = tid; c < 64 * 8; c += 256) {
            const int row = c >> 3, c4 = (c & 7) * 4;   // d = c4..c4+3 in [0,32)
            ushort4 lo = *(const ushort4*)&gq[(size_t)row * 512 + c4];
            ushort4 hi = *(const ushort4*)&gq[(size_t)row * 512 + c4 + 32];
            const float tstamp = (float)ts[tb + qlo + row];
            ushort4 olo, ohi;
#pragma unroll
            for (int j2 = 0; j2 < 4; ++j2) {
                const float freq = __expf(-0.2878231366242558f * (float)(c4 + j2));
                const float ang = tstamp * freq;
                const float cc = __cosf(ang), ss = __sinf(ang);
                const float v1 = bf2f(((const unsigned short*)&lo)[j2]);
                const float v2 = bf2f(((const unsigned short*)&hi)[j2]);
                ((unsigned short*)&olo)[j2] = f2bf(v1 * cc - v2 * ss);
                ((unsigned short*)&ohi)[j2] = f2bf(v2 * cc + v1 * ss);
            }
            *(ushort4*)&Qs[row * AKS + c4]      = olo;
            *(ushort4*)&Qs[row * AKS + c4 + 32] = ohi;
        }
    }
    // ---- stage K with RoPE ----
    {
        const unsigned short* gk = k + ((size_t)(tb + klo)) * 512 + h * 64;
        for (int c = tid; c < AWIN * 8; c += 256) {
            const int row = c >> 3, c4 = (c & 7) * 4;
            ushort4 lo = *(const ushort4*)&gk[(size_t)row * 512 + c4];
            ushort4 hi = *(const ushort4*)&gk[(size_t)row * 512 + c4 + 32];
            const float tstamp = (float)ts[tb + klo + row];
            ushort4 olo, ohi;
#pragma unroll
            for (int j2 = 0; j2 < 4; ++j2) {
                const float freq = __expf(-0.2878231366242558f * (float)(c4 + j2));
                const float ang = tstamp * freq;
                const float cc = __cosf(ang), ss = __sinf(ang);
                const float v1 = bf2f(((const unsigned short*)&lo)[j2]);
                const float v2 = bf2f(((const unsigned short*)&hi)[j2]);
                ((unsigned short*)&olo)[j2] = f2bf(v1 * cc - v2 * ss);
                ((unsigned short*)&ohi)[j2] = f2bf(v2 * cc + v1 * ss);
            }
            *(ushort4*)&Ks[row * AKS + c4]      = olo;
            *(ushort4*)&Ks[row * AKS + c4 + 32] = ohi;
        }
    }
    // ---- stage V (transposed into LDS) ----
    {
        const unsigned short* gv = v + ((size_t)(tb + klo)) * 512 + h * 64;
        for (int c = tid; c < AWIN * 16; c += 256) {
            const int row = c >> 4, c4 = (c & 15) * 4;
            ushort4 vv = *(const ushort4*)&gv[(size_t)row * 512 + c4];
            Vt[(c4 + 0) * AVS + row] = vv.x;
            Vt[(c4 + 1) * AVS + row] = vv.y;
            Vt[(c4 + 2) * AVS + row] = vv.z;
            Vt[(c4 + 3) * AVS + row] = vv.w;
        }
    }
    __syncthreads();

    // ---- S = Q @ K^T ----
    f32x4 accs[12];
    {
        const bf16x8 a0 = *(const bf16x8*)&Qs[(w * 16 + l16) * AKS + g16 * 8];
        const bf16x8 a1 = *(const bf16x8*)&Qs[(w * 16 + l16) * AKS + 32 + g16 * 8];
#pragma unroll
        for (int t = 0; t < 12; ++t) {
            const bf16x8 b0 = *(const bf16x8*)&Ks[(t * 16 + l16) * AKS + g16 * 8];
            const bf16x8 b1 = *(const bf16x8*)&Ks[(t * 16 + l16) * AKS + 32 + g16 * 8];
            f32x4 c = {};
            c = __builtin_amdgcn_mfma_f32_16x16x32_bf16(a0, b0, c, 0, 0, 0);
            c = __builtin_amdgcn_mfma_f32_16x16x32_bf16(a1, b1, c, 0, 0, 0);
            accs[t] = c;
        }
    }

    // ---- softmax in registers ----
    bool mk[12];
    int  jj[12];
#pragma unroll
    for (int t = 0; t < 12; ++t) {
        jj[t] = klo + t * 16 + l16;
        mk[t] = smask[tb + jj[t]] > 0;
    }

    float rs[4];
#pragma unroll
    for (int r = 0; r < 4; ++r) {
        const int i = qlo + 16 * w + g16 * 4 + r;
        float mx = -1e30f;
#pragma unroll
        for (int t = 0; t < 12; ++t) {
            const bool val = mk[t] && (jj[t] >= i - CB_) && (jj[t] <= i);
            mx = fmaxf(mx, val ? accs[t][r] : -1e30f);
        }
        mx = fmaxf(mx, __shfl_xor(mx, 1));
        mx = fmaxf(mx, __shfl_xor(mx, 2));
        mx = fmaxf(mx, __shfl_xor(mx, 4));
        mx = fmaxf(mx, __shfl_xor(mx, 8));
        float sum = 0.0f;
#pragma unroll
        for (int t = 0; t < 12; ++t) {
            const bool val = mk[t] && (jj[t] >= i - CB_) && (jj[t] <= i);
            const float p = val ? __expf(accs[t][r] - mx) : 0.0f;
            accs[t][r] = p;
            sum += p;
        }
        sum += __shfl_xor(sum, 1);
        sum += __shfl_xor(sum, 2);
        sum += __shfl_xor(sum, 4);
        sum += __shfl_xor(sum, 8);
        rs[r] = 1.0f / sum;
    }

    // Ks dead from here; Pb aliases it.
    __syncthreads();

    // ---- P -> LDS ----
#pragma unroll
    for (int t = 0; t < 12; ++t)
#pragma unroll
        for (int r = 0; r < 4; ++r)
            Pb[(16 * w + g16 * 4 + r) * AVS + t * 16 + l16] = f2bf(accs[t][r]);

    // ---- O = P @ V ----
    f32x4 acco[4];
#pragma unroll
    for (int nt = 0; nt < 4; ++nt) {
        f32x4 c = {};
#pragma unroll
        for (int ks = 0; ks < 6; ++ks) {
            const bf16x8 a = *(const bf16x8*)&Pb[(16 * w + l16) * AVS + ks * 32 + g16 * 8];
            const bf16x8 bb = *(const bf16x8*)&Vt[(nt * 16 + l16) * AVS + ks * 32 + g16 * 8];
            c = __builtin_amdgcn_mfma_f32_16x16x32_bf16(a, bb, c, 0, 0, 0);
        }
        acco[nt] = c;
    }

    // ---- stage O into Pb, vector store ----
    __syncthreads();
#pragma unroll
    for (int nt = 0; nt < 4; ++nt)
#pragma unroll
        for (int r = 0; r < 4; ++r)
            Pb[(16 * w + g16 * 4 + r) * AVS + nt * 16 + l16] = f2bf(acco[nt][r] * rs[r]);

    const int row16 = lane >> 2, cg = lane & 3;
    const int grow = tb + qlo + 16 * w + row16;
#pragma unroll
    for (int s = 0; s < 4; ++s) {
        ushort4 t4 = *(const ushort4*)&Pb[(16 * w + row16) * AVS + s * 16 + cg * 4];
        *(ushort4*)&o[(size_t)grow * 512 + h * 64 + s * 16 + cg * 4] = t4;
    }
}

// ---------------------------------------------------------------------------
extern "C" void kernel_launch(void* const* d_in, const int* in_sizes, int n_in,
                              void* d_out, int out_size, void* d_ws, size_t ws_size,
                              hipStream_t stream)
{
    const float* spikes  = (const float*)d_in[0];
    const int*   smask   = (const int*)d_in[1];
    const int*   ts      = (const int*)d_in[2];
    const float* embed_w = (const float*)d_in[3];
    const float* embed_b = (const float*)d_in[4];
    const float* proj_w  = (const float*)d_in[5];
    const float* proj_b  = (const float*)d_in[6];
    const float* ln1_g   = (const float*)d_in[7];
    const float* ln1_b   = (const float*)d_in[8];
    const float* Wq      = (const float*)d_in[9];
    const float* bq      = (const float*)d_in[10];
    const float* Wk      = (const float*)d_in[11];
    const float* bk      = (const float*)d_in[12];
    const float* Wv      = (const float*)d_in[13];
    const float* bv      = (const float*)d_in[14];
    const float* Wo      = (const float*)d_in[15];
    const float* bo      = (const float*)d_in[16];
    const float* ln2_g   = (const float*)d_in[17];
    const float* ln2_b   = (const float*)d_in[18];
    const float* up_w    = (const float*)d_in[19];
    const float* up_b    = (const float*)d_in[20];
    const float* down_w  = (const float*)d_in[21];
    const float* down_b  = (const float*)d_in[22];

    const int M = B_ * T_;  // 4096

    char* p = (char*)d_ws;
    float* x = (float*)p;                       p += (size_t)M * H_ * 4;
    unsigned short* qb  = (unsigned short*)p;   p += (size_t)M * H_ * 2;
    unsigned short* kb  = (unsigned short*)p;   p += (size_t)M * H_ * 2;
    unsigned short* vb  = (unsigned short*)p;   p += (size_t)M * H_ * 2;
    unsigned short* hbf = (unsigned short*)p;   p += (size_t)M * H_ * 2;
    unsigned short* obf = (unsigned short*)p;   p += (size_t)M * H_ * 2;
    unsigned short* ibf = (unsigned short*)p;   p += (size_t)M * INTER_ * 2;
    unsigned short* tbf = (unsigned short*)p;   p += (size_t)M * D_ * 2;
    unsigned short* spbf  = (unsigned short*)p; p += (size_t)M * C_ * 2;
    unsigned short* embT  = (unsigned short*)p; p += (size_t)D_ * C_ * 2;
    unsigned short* projT = (unsigned short*)p; p += (size_t)H_ * D_ * 2;
    unsigned short* qkvT  = (unsigned short*)p; p += (size_t)L_ * 3 * H_ * H_ * 2;
    unsigned short* woT   = (unsigned short*)p; p += (size_t)L_ * H_ * H_ * 2;
    unsigned short* upT   = (unsigned short*)p; p += (size_t)L_ * INTER_ * H_ * 2;
    unsigned short* downT = (unsigned short*)p; p += (size_t)L_ * H_ * INTER_ * 2;

    // ---- fused prologue: all weight transposes + spikes convert, 1 dispatch
    prep_k<<<3376, 256, 0, stream>>>(
        spikes, embed_w, proj_w, Wq, Wk, Wv, Wo, up_w, down_w,
        spbf, embT, projT, qkvT, woT, upT, downT);

    // ---- embedding ----
    mm64_k<1, 0, 1, 0><<<dim3(D_ / 64, M / 64), 256, 0, stream>>>(
        spbf, embT, embed_b, nullptr, nullptr, nullptr,
        tbf, nullptr, nullptr, M, D_, C_);
    mm64_k<0, 0, 0, 0><<<dim3(H_ / 64, M / 64), 256, 0, stream>>>(
        tbf, projT, proj_b, nullptr, nullptr, nullptr,
        x, nullptr, nullptr, M, H_, D_);

    for (int l = 0; l < L_; ++l) {
        const unsigned short* qkvT_l = qkvT + (size_t)l * 3 * H_ * H_;
        const unsigned short* woT_l  = woT  + (size_t)l * H_ * H_;
        const unsigned short* upT_l  = upT  + (size_t)l * INTER_ * H_;
        const unsigned short* dnT_l  = downT + (size_t)l * H_ * INTER_;

        ln_k<<<M, 256, 0, stream>>>(x, ln1_g + l * H_, ln1_b + l * H_, hbf);

        // fused QKV + bias (+0.125 q scale) -> qb, kb, vb (bf16 [M,512])
        // 128x64 tile: grid 24x32 = 768 blocks = 3 blocks/CU
        mm128_k<0, 0, 1, 1><<<dim3((3 * H_) / 64, M / 128), 256, 0, stream>>>(
            hbf, qkvT_l, bq + l * H_, bk + l * H_, bv + l * H_, nullptr,
            qb, kb, vb, M, 3 * H_, H_);

        // attention (RoPE fused into staging)
        attn_k<<<B_ * NH_ * (T_ / 64), 256, 0, stream>>>(qb, kb, vb, smask, ts, obf);

        // x = x + obuf @ Wo + bo  (64x64: grid 512 = 2 blocks/CU)
        mm64_k<0, 1, 0, 0><<<dim3(H_ / 64, M / 64), 256, 0, stream>>>(
            obf, woT_l, bo + l * H_, nullptr, nullptr, x,
            x, nullptr, nullptr, M, H_, H_);

        ln_k<<<M, 256, 0, stream>>>(x, ln2_g + l * H_, ln2_b + l * H_, hbf);

        // inter = gelu(h @ up_w + b)  (128x64: grid 32x32 = 1024 blocks)
        mm128_k<1, 0, 1, 0><<<dim3(INTER_ / 64, M / 128), 256, 0, stream>>>(
            hbf, upT_l, up_b + l * INTER_, nullptr, nullptr, nullptr,
            ibf, nullptr, nullptr, M, INTER_, H_);

        // x = x + inter @ down_w + b  (64x64: grid 512 = 2 blocks/CU)
        float* dst = (l == L_ - 1) ? (float*)d_out : x;
        mm64_k<0, 1, 0, 0><<<dim3(H_ / 64, M / 64), 256, 0, stream>>>(
            ibf, dnT_l, down_b + l * H_, nullptr, nullptr, x,
            dst, nullptr, nullptr, M, H_, INTER_);
    }
}

// Round 5
// 497.920 us; speedup vs baseline: 1.1286x; 1.0751x over previous
//
#include <hip/hip_runtime.h>
#include <math.h>

// Problem dims (fixed)
#define B_ 4
#define T_ 1024
#define C_ 256
#define D_ 256
#define H_ 512
#define NH_ 8
#define HD_ 64
#define INTER_ 2048
#define L_ 4
#define CB_ 128   // context_backward; context_forward = 0

typedef short bf16x8 __attribute__((ext_vector_type(8)));
typedef unsigned short ush8 __attribute__((ext_vector_type(8)));
typedef float f32x4 __attribute__((ext_vector_type(4)));

__device__ __forceinline__ float gelu_exact(float x) {
    return 0.5f * x * (1.0f + erff(x * 0.70710678118654752f));
}

// fp32 -> bf16 round-to-nearest-even
__device__ __forceinline__ unsigned short f2bf(float f) {
    unsigned u = __float_as_uint(f);
    u += 0x7fffu + ((u >> 16) & 1u);
    return (unsigned short)(u >> 16);
}
__device__ __forceinline__ float bf2f(unsigned short h) {
    return __uint_as_float((unsigned)h << 16);
}

// XCD-chunked bijective block swizzle (T1). Requires nwg % 8 == 0.
__device__ __forceinline__ void xcd_swz(int& bx, int& by) {
    const int gx  = gridDim.x;
    const int nwg = gx * gridDim.y;
    int bid = blockIdx.y * gx + blockIdx.x;
    bid = (bid & 7) * (nwg >> 3) + (bid >> 3);
    bx = bid % gx;
    by = bid / gx;
}

// ---------------------------------------------------------------------------
// bf16 MFMA GEMM, 64x64 tile, BK=128 (two 64-col halves staged per barrier
// pair), XOR-swizzled LDS. vs R2's BK=64: the full vmcnt(0)+barrier drain
// happens K/128 times instead of K/64 -- halves the dominant stall on the
// deep-K down-projection (R4 lesson: dbuf does NOT fix this; fewer drains
// does). LDS 32 KB; occupancy stays grid-limited (>=2 blocks/CU).
// ---------------------------------------------------------------------------
template<int ACT, int RES, int OBF, int SPLIT>
__global__ __launch_bounds__(256) void mm64_k(
    const unsigned short* __restrict__ A, const unsigned short* __restrict__ BT,
    const float* __restrict__ b0, const float* __restrict__ b1,
    const float* __restrict__ b2,
    const float* res,
    void* o0, void* o1, void* o2,
    const int M, const int N, const int K)
{
    __shared__ unsigned short As[2][64 * 64];
    __shared__ unsigned short Bs[2][64 * 64];

    int bx, by; xcd_swz(bx, by);

    const int tid  = threadIdx.x;
    const int lane = tid & 63;
    const int w    = tid >> 6;
    const int m0   = by * 64;
    const int n0   = bx * 64;
    const int wm   = (w >> 1) * 32;
    const int wn   = (w & 1) * 32;
    const int l16  = lane & 15;
    const int g16  = lane >> 4;

    f32x4 acc[2][2] = {};

    const unsigned short* Abase = A  + (size_t)m0 * K;
    const unsigned short* Bbase = BT + (size_t)n0 * K;

    // staging chunks: c0 = w*64+lane (rows 8w..8w+7), c1 = c0+256 (rows 32..63)
    const int c0 = (w << 6) + lane;
    const int c1 = c0 + 256;
    const int r0c = c0 >> 3, gk0 = (c0 & 7) ^ (r0c & 7);
    const int r1c = c1 >> 3, gk1 = (c1 & 7) ^ (r1c & 7);

#define STAGE64(buf, kk0) do {                                                                        \
    __builtin_amdgcn_global_load_lds(                                                                 \
        (const __attribute__((address_space(1))) unsigned*)(Abase + (size_t)r0c * K + (kk0) + gk0 * 8), \
        (__attribute__((address_space(3))) unsigned*)(As[buf] + (size_t)(w << 6) * 8), 16, 0, 0);     \
    __builtin_amdgcn_global_load_lds(                                                                 \
        (const __attribute__((address_space(1))) unsigned*)(Abase + (size_t)r1c * K + (kk0) + gk1 * 8), \
        (__attribute__((address_space(3))) unsigned*)(As[buf] + (size_t)(256 + (w << 6)) * 8), 16, 0, 0); \
    __builtin_amdgcn_global_load_lds(                                                                 \
        (const __attribute__((address_space(1))) unsigned*)(Bbase + (size_t)r0c * K + (kk0) + gk0 * 8), \
        (__attribute__((address_space(3))) unsigned*)(Bs[buf] + (size_t)(w << 6) * 8), 16, 0, 0);     \
    __builtin_amdgcn_global_load_lds(                                                                 \
        (const __attribute__((address_space(1))) unsigned*)(Bbase + (size_t)r1c * K + (kk0) + gk1 * 8), \
        (__attribute__((address_space(3))) unsigned*)(Bs[buf] + (size_t)(256 + (w << 6)) * 8), 16, 0, 0); \
} while (0)

    for (int k0 = 0; k0 < K; k0 += 128) {
        __syncthreads();                 // LDS reuse guard (no loads in flight)
        STAGE64(0, k0);
        STAGE64(1, k0 + 64);
        __syncthreads();                 // implicit vmcnt(0): both halves landed

#pragma unroll
        for (int half = 0; half < 2; ++half) {
#pragma unroll
            for (int kk = 0; kk < 2; ++kk) {
                const int kf = kk * 4 + g16;            // k-group 0..7 in half
                const int sw = (kf ^ (l16 & 7)) * 8;    // swizzled ushort offset
                bf16x8 a[2], b[2];
#pragma unroll
                for (int t = 0; t < 2; ++t)
                    a[t] = *(const bf16x8*)&As[half][(wm + t * 16 + l16) * 64 + sw];
#pragma unroll
                for (int t = 0; t < 2; ++t)
                    b[t] = *(const bf16x8*)&Bs[half][(wn + t * 16 + l16) * 64 + sw];
#pragma unroll
                for (int i = 0; i < 2; ++i)
#pragma unroll
                    for (int j = 0; j < 2; ++j)
                        acc[i][j] = __builtin_amdgcn_mfma_f32_16x16x32_bf16(a[i], b[j], acc[i][j], 0, 0, 0);
            }
        }
    }
#undef STAGE64

    if (OBF || SPLIT) {
        __syncthreads();
        unsigned short* Eb = ((w < 2) ? As[0] : Bs[0]) + (w & 1) * 1024;
        const int row16 = lane >> 2;
        const int cg    = lane & 3;

        const int gnb   = n0 + wn;
        const int which = SPLIT ? (gnb >> 9) : 0;
        const int lnb   = SPLIT ? (gnb & 511) : gnb;
        const int ldo   = SPLIT ? 512 : N;
        unsigned short* oo = SPLIT
            ? ((which == 0) ? (unsigned short*)o0 : (which == 1) ? (unsigned short*)o1 : (unsigned short*)o2)
            : (unsigned short*)o0;
        const float* bb = SPLIT ? ((which == 0) ? b0 : (which == 1) ? b1 : b2) : b0;
        const float scale = (SPLIT && which == 0) ? 0.125f : 1.0f;

#pragma unroll
        for (int i = 0; i < 2; ++i) {
#pragma unroll
            for (int j = 0; j < 2; ++j) {
                const float bv = bb[lnb + j * 16 + l16];
#pragma unroll
                for (int r = 0; r < 4; ++r) {
                    float cv = acc[i][j][r] + bv;
                    if (ACT) cv = gelu_exact(cv);
                    if (SPLIT) cv *= scale;
                    Eb[(g16 * 4 + r) * 40 + j * 16 + l16] = f2bf(cv);
                }
            }
            const int grow0 = m0 + wm + i * 16 + row16;
#pragma unroll
            for (int s = 0; s < 2; ++s) {
                ushort4 t4 = *(const ushort4*)&Eb[row16 * 40 + s * 16 + cg * 4];
                *(ushort4*)&oo[(size_t)grow0 * ldo + lnb + s * 16 + cg * 4] = t4;
            }
        }
        return;
    }

    // fp32 out epilogue (scalar 4B stores = full 64B runs per 16 lanes)
#pragma unroll
    for (int i = 0; i < 2; ++i) {
        const int gmb = m0 + wm + i * 16 + g16 * 4;
#pragma unroll
        for (int j = 0; j < 2; ++j) {
            const int gn = n0 + wn + j * 16 + l16;
            const float bv = b0[gn];
#pragma unroll
            for (int r = 0; r < 4; ++r) {
                float cv = acc[i][j][r] + bv;
                if (ACT) cv = gelu_exact(cv);
                if (RES) cv += res[(size_t)(gmb + r) * 512 + gn];
                ((float*)o0)[(size_t)(gmb + r) * N + gn] = cv;
            }
        }
    }
}

// ---------------------------------------------------------------------------
// bf16 MFMA GEMM, 128x64 tile, BK=64 (R2-proven config for QKV/up).
// ---------------------------------------------------------------------------
template<int ACT, int RES, int OBF, int SPLIT>
__global__ __launch_bounds__(256) void mm128_k(
    const unsigned short* __restrict__ A, const unsigned short* __restrict__ BT,
    const float* __restrict__ b0, const float* __restrict__ b1,
    const float* __restrict__ b2,
    const float* res,
    void* o0, void* o1, void* o2,
    const int M, const int N, const int K)
{
    __shared__ unsigned short As[128 * 64];
    __shared__ unsigned short Bs[64 * 64];

    int bx, by; xcd_swz(bx, by);

    const int tid  = threadIdx.x;
    const int lane = tid & 63;
    const int w    = tid >> 6;
    const int m0   = by * 128;
    const int n0   = bx * 64;
    const int wm   = (w >> 1) * 64;       // 0 or 64
    const int wn   = (w & 1) * 32;        // 0 or 32
    const int l16  = lane & 15;
    const int g16  = lane >> 4;

    f32x4 acc[4][2] = {};

    const unsigned short* Abase = A  + (size_t)m0 * K;
    const unsigned short* Bbase = BT + (size_t)n0 * K;

    for (int k0 = 0; k0 < K; k0 += 64) {
        __syncthreads();
        // A tile: 128 rows x 64 cols = 1024 16B chunks, 4 issues/thread
#pragma unroll
        for (int it = 0; it < 4; ++it) {
            const int c = it * 256 + tid;
            const int rc = c >> 3, gk = (c & 7) ^ (rc & 7);
            __builtin_amdgcn_global_load_lds(
                (const __attribute__((address_space(1))) unsigned*)(Abase + (size_t)rc * K + k0 + gk * 8),
                (__attribute__((address_space(3))) unsigned*)(As + (size_t)(it * 256 + (w << 6)) * 8), 16, 0, 0);
        }
        // B tile: 64 rows x 64 cols, 2 issues/thread
#pragma unroll
        for (int it = 0; it < 2; ++it) {
            const int c = it * 256 + tid;
            const int rc = c >> 3, gk = (c & 7) ^ (rc & 7);
            __builtin_amdgcn_global_load_lds(
                (const __attribute__((address_space(1))) unsigned*)(Bbase + (size_t)rc * K + k0 + gk * 8),
                (__attribute__((address_space(3))) unsigned*)(Bs + (size_t)(it * 256 + (w << 6)) * 8), 16, 0, 0);
        }
        __syncthreads();

#pragma unroll
        for (int kk = 0; kk < 2; ++kk) {
            const int kf = kk * 4 + g16;            // global k-group 0..7
            const int sw = (kf ^ (l16 & 7)) * 8;    // swizzled ushort offset
            bf16x8 a[4], b[2];
#pragma unroll
            for (int t = 0; t < 4; ++t)
                a[t] = *(const bf16x8*)&As[(wm + t * 16 + l16) * 64 + sw];
#pragma unroll
            for (int t = 0; t < 2; ++t)
                b[t] = *(const bf16x8*)&Bs[(wn + t * 16 + l16) * 64 + sw];
#pragma unroll
            for (int i = 0; i < 4; ++i)
#pragma unroll
                for (int j = 0; j < 2; ++j)
                    acc[i][j] = __builtin_amdgcn_mfma_f32_16x16x32_bf16(a[i], b[j], acc[i][j], 0, 0, 0);
        }
    }

    if (OBF || SPLIT) {
        __syncthreads();
        constexpr int EST = 40;               // Eb stride (pad breaks 4-way)
        unsigned short* Eb = As + w * (16 * EST);
        const int erow = lane >> 3;           // 8 lanes per 32-col row
        const int ecol = (lane & 7) * 4;

        const int gnb   = n0 + wn;
        const int which = SPLIT ? (gnb >> 9) : 0;
        const int lnb   = SPLIT ? (gnb & 511) : gnb;
        const int ldo   = SPLIT ? 512 : N;
        unsigned short* oo = SPLIT
            ? ((which == 0) ? (unsigned short*)o0 : (which == 1) ? (unsigned short*)o1 : (unsigned short*)o2)
            : (unsigned short*)o0;
        const float* bb = SPLIT ? ((which == 0) ? b0 : (which == 1) ? b1 : b2) : b0;
        const float scale = (SPLIT && which == 0) ? 0.125f : 1.0f;

#pragma unroll
        for (int i = 0; i < 4; ++i) {
#pragma unroll
            for (int j = 0; j < 2; ++j) {
                const float bv = bb[lnb + j * 16 + l16];
#pragma unroll
                for (int r = 0; r < 4; ++r) {
                    float cv = acc[i][j][r] + bv;
                    if (ACT) cv = gelu_exact(cv);
                    if (SPLIT) cv *= scale;
                    Eb[(g16 * 4 + r) * EST + j * 16 + l16] = f2bf(cv);
                }
            }
            const int grow0 = m0 + wm + i * 16;
#pragma unroll
            for (int s = 0; s < 2; ++s) {
                ushort4 t4 = *(const ushort4*)&Eb[(s * 8 + erow) * EST + ecol];
                *(ushort4*)&oo[(size_t)(grow0 + s * 8 + erow) * ldo + lnb + ecol] = t4;
            }
        }
        return;
    }

    // fp32 out epilogue
#pragma unroll
    for (int i = 0; i < 4; ++i) {
        const int gmb = m0 + wm + i * 16 + g16 * 4;
#pragma unroll
        for (int j = 0; j < 2; ++j) {
            const int gn = n0 + wn + j * 16 + l16;
            const float bv = b0[gn];
#pragma unroll
            for (int r = 0; r < 4; ++r) {
                float cv = acc[i][j][r] + bv;
                if (ACT) cv = gelu_exact(cv);
                if (RES) cv += res[(size_t)(gmb + r) * 512 + gn];
                ((float*)o0)[(size_t)(gmb + r) * N + gn] = cv;
            }
        }
    }
}

// ---------------------------------------------------------------------------
// Fused prologue: ONE dispatch for all weight transposes + spikes convert.
// ---------------------------------------------------------------------------
__global__ __launch_bounds__(256) void prep_k(
    const float* __restrict__ spikes,
    const float* __restrict__ embed_w, const float* __restrict__ proj_w,
    const float* __restrict__ Wq, const float* __restrict__ Wk,
    const float* __restrict__ Wv, const float* __restrict__ Wo,
    const float* __restrict__ up_w, const float* __restrict__ down_w,
    unsigned short* __restrict__ spbf,
    unsigned short* __restrict__ embT, unsigned short* __restrict__ projT,
    unsigned short* __restrict__ qkvT, unsigned short* __restrict__ woT,
    unsigned short* __restrict__ upT, unsigned short* __restrict__ downT)
{
    const int idx = blockIdx.x;
    const int tid = threadIdx.x;

    if (idx >= 3120) {  // spikes fp32->bf16: 256 blocks x 4096 elems
        const int base = (idx - 3120) * 4096 + tid * 16;
#pragma unroll
        for (int s = 0; s < 4; ++s) {
            float4 v = *(const float4*)&spikes[base + s * 4];
            ushort4 o = {f2bf(v.x), f2bf(v.y), f2bf(v.z), f2bf(v.w)};
            *(ushort4*)&spbf[base + s * 4] = o;
        }
        return;
    }

    const float* src; unsigned short* dst; int R, Cc, t;
    if (idx < 16)      { src = embed_w; dst = embT;  R = C_; Cc = D_; t = idx; }
    else if (idx < 48) { src = proj_w;  dst = projT; R = D_; Cc = H_; t = idx - 16; }
    else if (idx < 816) {
        const int j = idx - 48;        // 0..767: Wq | Wk | Wv, 4 layers x 64 tiles
        const int wsel = j >> 8;
        const int l = (j & 255) >> 6;
        t = j & 63;
        src = ((wsel == 0) ? Wq : (wsel == 1) ? Wk : Wv) + (size_t)l * H_ * H_;
        dst = qkvT + (size_t)l * 3 * H_ * H_ + (size_t)wsel * H_ * H_;
        R = H_; Cc = H_;
    } else if (idx < 1072) {
        const int j = idx - 816; const int l = j >> 6; t = j & 63;
        src = Wo + (size_t)l * H_ * H_; dst = woT + (size_t)l * H_ * H_;
        R = H_; Cc = H_;
    } else if (idx < 2096) {
        const int j = idx - 1072; const int l = j >> 8; t = j & 255;
        src = up_w + (size_t)l * H_ * INTER_; dst = upT + (size_t)l * INTER_ * H_;
        R = H_; Cc = INTER_;
    } else {
        const int j = idx - 2096; const int l = j >> 8; t = j & 255;
        src = down_w + (size_t)l * INTER_ * H_; dst = downT + (size_t)l * H_ * INTER_;
        R = INTER_; Cc = H_;
    }
    const int ntx = Cc >> 6;
    const int c0 = (t % ntx) * 64, r0 = (t / ntx) * 64;

    __shared__ float tile[64][65];
    const int tr = tid >> 4, tc = (tid & 15) * 4;
#pragma unroll
    for (int i = 0; i < 4; ++i) {
        float4 v = *(const float4*)&src[(size_t)(r0 + tr + i * 16) * Cc + c0 + tc];
        tile[tr + i * 16][tc + 0] = v.x;
        tile[tr + i * 16][tc + 1] = v.y;
        tile[tr + i * 16][tc + 2] = v.z;
        tile[tr + i * 16][tc + 3] = v.w;
    }
    __syncthreads();
#pragma unroll
    for (int i = 0; i < 4; ++i) {
        const int n = tr + i * 16;
        ushort4 o;
        o.x = f2bf(tile[tc + 0][n]);
        o.y = f2bf(tile[tc + 1][n]);
        o.z = f2bf(tile[tc + 2][n]);
        o.w = f2bf(tile[tc + 3][n]);
        *(ushort4*)&dst[(size_t)(c0 + n) * R + r0 + tc] = o;
    }
}

// ---------------------------------------------------------------------------
// LayerNorm over H=512, bf16 output.
// ---------------------------------------------------------------------------
__global__ __launch_bounds__(256) void ln_k(
    const float* __restrict__ x, const float* __restrict__ g,
    const float* __restrict__ b, unsigned short* __restrict__ out)
{
    const int row = blockIdx.x;
    const int tid = threadIdx.x;
    const float* xr = x + (size_t)row * H_;

    float v0 = xr[tid];
    float v1 = xr[tid + 256];

    float s = v0 + v1;
#pragma unroll
    for (int off = 32; off; off >>= 1) s += __shfl_xor(s, off);

    __shared__ float red[4];
    const int wave = tid >> 6;
    if ((tid & 63) == 0) red[wave] = s;
    __syncthreads();
    const float mean = (red[0] + red[1] + red[2] + red[3]) * (1.0f / (float)H_);

    const float d0 = v0 - mean, d1 = v1 - mean;
    float q = d0 * d0 + d1 * d1;
#pragma unroll
    for (int off = 32; off; off >>= 1) q += __shfl_xor(q, off);
    __syncthreads();
    if ((tid & 63) == 0) red[wave] = q;
    __syncthreads();
    const float var = (red[0] + red[1] + red[2] + red[3]) * (1.0f / (float)H_);
    const float rstd = rsqrtf(var + 1e-5f);

    out[(size_t)row * H_ + tid]       = f2bf(d0 * rstd * g[tid] + b[tid]);
    out[(size_t)row * H_ + tid + 256] = f2bf(d1 * rstd * g[tid + 256] + b[tid + 256]);
}

// ---------------------------------------------------------------------------
// MFMA banded attention. RoPE'd Q now built in REGISTERS (the S-pass a-frag
// cols g16*8..+7 / +32 are exactly a RoPE pair set per lane) -- removes the
// Qs LDS buffer and its staging phase. LDS 52 KB -> 3 blocks/CU (was 61 KB
// -> 2), +50% TLP for this staging-latency-heavy kernel.
// ---------------------------------------------------------------------------
#define AWIN 192
#define AKS 72
#define AVS 200

__global__ __launch_bounds__(256) void attn_k(
    const unsigned short* __restrict__ q, const unsigned short* __restrict__ k,
    const unsigned short* __restrict__ v, const int* __restrict__ smask,
    const int* __restrict__ ts, unsigned short* __restrict__ o)
{
    __shared__ unsigned short Ks[AWIN * AKS];   // reused as Pb after S-pass
    __shared__ unsigned short Vt[64 * AVS];
    unsigned short* const Pb = Ks;              // 64*AVS = 12800 <= 13824

    const int blk = blockIdx.x;
    const int qt = blk & 15;
    const int h  = (blk >> 4) & 7;
    const int b  = blk >> 7;
    const int tid  = threadIdx.x;
    const int lane = tid & 63;
    const int w    = tid >> 6;
    const int l16  = lane & 15;
    const int g16  = lane >> 4;

    const int qlo = qt * 64;
    const int klo = (qlo >= CB_) ? (qlo - CB_) : 0;
    const int tb  = b * 1024;

    // ---- Q with RoPE, straight into the a-frag registers ----
    // lane (l16,g16) covers row w*16+l16, cols g16*8..+7 (pairs with +32).
    bf16x8 qa0, qa1;
    {
        const int qrow = w * 16 + l16;
        const unsigned short* gq = q + ((size_t)(tb + qlo + qrow)) * 512 + h * 64;
        ush8 lo = *(const ush8*)&gq[g16 * 8];
        ush8 hi = *(const ush8*)&gq[g16 * 8 + 32];
        const float tstamp = (float)ts[tb + qlo + qrow];
#pragma unroll
        for (int j = 0; j < 8; ++j) {
            const int d = g16 * 8 + j;
            const float freq = __expf(-0.2878231366242558f * (float)d);
            const float ang = tstamp * freq;
            const float cc = __cosf(ang), ss = __sinf(ang);
            const float v1 = bf2f(lo[j]);
            const float v2 = bf2f(hi[j]);
            ((unsigned short*)&qa0)[j] = f2bf(v1 * cc - v2 * ss);
            ((unsigned short*)&qa1)[j] = f2bf(v2 * cc + v1 * ss);
        }
    }

    // ---- stage K with RoPE ----
    {
        const unsigned short* gk = k + ((size_t)(tb + klo)) * 512 + h * 64;
        for (int c = tid; c < AWIN * 8; c += 256) {
            const int row = c >> 3, c4 = (c & 7) * 4;
            ushort4 lo = *(const ushort4*)&gk[(size_t)row * 512 + c4];
            ushort4 hi = *(const ushort4*)&gk[(size_t)row * 512 + c4 + 32];
            const float tstamp = (float)ts[tb + klo + row];
            ushort4 olo, ohi;
#pragma unroll
            for (int j2 = 0; j2 < 4; ++j2) {
                const float freq = __expf(-0.2878231366242558f * (float)(c4 + j2));
                const float ang = tstamp * freq;
                const float cc = __cosf(ang), ss = __sinf(ang);
                const float v1 = bf2f(((const unsigned short*)&lo)[j2]);
                const float v2 = bf2f(((const unsigned short*)&hi)[j2]);
                ((unsigned short*)&olo)[j2] = f2bf(v1 * cc - v2 * ss);
                ((unsigned short*)&ohi)[j2] = f2bf(v2 * cc + v1 * ss);
            }
            *(ushort4*)&Ks[row * AKS + c4]      = olo;
            *(ushort4*)&Ks[row * AKS + c4 + 32] = ohi;
        }
    }
    // ---- stage V (transposed into LDS) ----
    {
        const unsigned short* gv = v + ((size_t)(tb + klo)) * 512 + h * 64;
        for (int c = tid; c < AWIN * 16; c += 256) {
            const int row = c >> 4, c4 = (c & 15) * 4;
            ushort4 vv = *(const ushort4*)&gv[(size_t)row * 512 + c4];
            Vt[(c4 + 0) * AVS + row] = vv.x;
            Vt[(c4 + 1) * AVS + row] = vv.y;
            Vt[(c4 + 2) * AVS + row] = vv.z;
            Vt[(c4 + 3) * AVS + row] = vv.w;
        }
    }
    __syncthreads();

    // ---- S = Q @ K^T ----
    f32x4 accs[12];
#pragma unroll
    for (int t = 0; t < 12; ++t) {
        const bf16x8 b0 = *(const bf16x8*)&Ks[(t * 16 + l16) * AKS + g16 * 8];
        const bf16x8 b1 = *(const bf16x8*)&Ks[(t * 16 + l16) * AKS + 32 + g16 * 8];
        f32x4 c = {};
        c = __builtin_amdgcn_mfma_f32_16x16x32_bf16(qa0, b0, c, 0, 0, 0);
        c = __builtin_amdgcn_mfma_f32_16x16x32_bf16(qa1, b1, c, 0, 0, 0);
        accs[t] = c;
    }

    // ---- softmax in registers ----
    bool mk[12];
    int  jj[12];
#pragma unroll
    for (int t = 0; t < 12; ++t) {
        jj[t] = klo + t * 16 + l16;
        mk[t] = smask[tb + jj[t]] > 0;
    }

    float rs[4];
#pragma unroll
    for (int r = 0; r < 4; ++r) {
        const int i = qlo + 16 * w + g16 * 4 + r;
        float mx = -1e30f;
#pragma unroll
        for (int t = 0; t < 12; ++t) {
            const bool val = mk[t] && (jj[t] >= i - CB_) && (jj[t] <= i);
            mx = fmaxf(mx, val ? accs[t][r] : -1e30f);
        }
        mx = fmaxf(mx, __shfl_xor(mx, 1));
        mx = fmaxf(mx, __shfl_xor(mx, 2));
        mx = fmaxf(mx, __shfl_xor(mx, 4));
        mx = fmaxf(mx, __shfl_xor(mx, 8));
        float sum = 0.0f;
#pragma unroll
        for (int t = 0; t < 12; ++t) {
            const bool val = mk[t] && (jj[t] >= i - CB_) && (jj[t] <= i);
            const float p = val ? __expf(accs[t][r] - mx) : 0.0f;
            accs[t][r] = p;
            sum += p;
        }
        sum += __shfl_xor(sum, 1);
        sum += __shfl_xor(sum, 2);
        sum += __shfl_xor(sum, 4);
        sum += __shfl_xor(sum, 8);
        rs[r] = 1.0f / sum;
    }

    // Ks dead from here; Pb aliases it.
    __syncthreads();

    // ---- P -> LDS ----
#pragma unroll
    for (int t = 0; t < 12; ++t)
#pragma unroll
        for (int r = 0; r < 4; ++r)
            Pb[(16 * w + g16 * 4 + r) * AVS + t * 16 + l16] = f2bf(accs[t][r]);

    // ---- O = P @ V ----
    f32x4 acco[4];
#pragma unroll
    for (int nt = 0; nt < 4; ++nt) {
        f32x4 c = {};
#pragma unroll
        for (int ks = 0; ks < 6; ++ks) {
            const bf16x8 a = *(const bf16x8*)&Pb[(16 * w + l16) * AVS + ks * 32 + g16 * 8];
            const bf16x8 bb = *(const bf16x8*)&Vt[(nt * 16 + l16) * AVS + ks * 32 + g16 * 8];
            c = __builtin_amdgcn_mfma_f32_16x16x32_bf16(a, bb, c, 0, 0, 0);
        }
        acco[nt] = c;
    }

    // ---- stage O into Pb, vector store ----
    __syncthreads();
#pragma unroll
    for (int nt = 0; nt < 4; ++nt)
#pragma unroll
        for (int r = 0; r < 4; ++r)
            Pb[(16 * w + g16 * 4 + r) * AVS + nt * 16 + l16] = f2bf(acco[nt][r] * rs[r]);

    const int row16 = lane >> 2, cg = lane & 3;
    const int grow = tb + qlo + 16 * w + row16;
#pragma unroll
    for (int s = 0; s < 4; ++s) {
        ushort4 t4 = *(const ushort4*)&Pb[(16 * w + row16) * AVS + s * 16 + cg * 4];
        *(ushort4*)&o[(size_t)grow * 512 + h * 64 + s * 16 + cg * 4] = t4;
    }
}

// ---------------------------------------------------------------------------
extern "C" void kernel_launch(void* const* d_in, const int* in_sizes, int n_in,
                              void* d_out, int out_size, void* d_ws, size_t ws_size,
                              hipStream_t stream)
{
    const float* spikes  = (const float*)d_in[0];
    const int*   smask   = (const int*)d_in[1];
    const int*   ts      = (const int*)d_in[2];
    const float* embed_w = (const float*)d_in[3];
    const float* embed_b = (const float*)d_in[4];
    const float* proj_w  = (const float*)d_in[5];
    const float* proj_b  = (const float*)d_in[6];
    const float* ln1_g   = (const float*)d_in[7];
    const float* ln1_b   = (const float*)d_in[8];
    const float* Wq      = (const float*)d_in[9];
    const float* bq      = (const float*)d_in[10];
    const float* Wk      = (const float*)d_in[11];
    const float* bk      = (const float*)d_in[12];
    const float* Wv      = (const float*)d_in[13];
    const float* bv      = (const float*)d_in[14];
    const float* Wo      = (const float*)d_in[15];
    const float* bo      = (const float*)d_in[16];
    const float* ln2_g   = (const float*)d_in[17];
    const float* ln2_b   = (const float*)d_in[18];
    const float* up_w    = (const float*)d_in[19];
    const float* up_b    = (const float*)d_in[20];
    const float* down_w  = (const float*)d_in[21];
    const float* down_b  = (const float*)d_in[22];

    const int M = B_ * T_;  // 4096

    char* p = (char*)d_ws;
    float* x = (float*)p;                       p += (size_t)M * H_ * 4;
    unsigned short* qb  = (unsigned short*)p;   p += (size_t)M * H_ * 2;
    unsigned short* kb  = (unsigned short*)p;   p += (size_t)M * H_ * 2;
    unsigned short* vb  = (unsigned short*)p;   p += (size_t)M * H_ * 2;
    unsigned short* hbf = (unsigned short*)p;   p += (size_t)M * H_ * 2;
    unsigned short* obf = (unsigned short*)p;   p += (size_t)M * H_ * 2;
    unsigned short* ibf = (unsigned short*)p;   p += (size_t)M * INTER_ * 2;
    unsigned short* tbf = (unsigned short*)p;   p += (size_t)M * D_ * 2;
    unsigned short* spbf  = (unsigned short*)p; p += (size_t)M * C_ * 2;
    unsigned short* embT  = (unsigned short*)p; p += (size_t)D_ * C_ * 2;
    unsigned short* projT = (unsigned short*)p; p += (size_t)H_ * D_ * 2;
    unsigned short* qkvT  = (unsigned short*)p; p += (size_t)L_ * 3 * H_ * H_ * 2;
    unsigned short* woT   = (unsigned short*)p; p += (size_t)L_ * H_ * H_ * 2;
    unsigned short* upT   = (unsigned short*)p; p += (size_t)L_ * INTER_ * H_ * 2;
    unsigned short* downT = (unsigned short*)p; p += (size_t)L_ * H_ * INTER_ * 2;

    // ---- fused prologue: all weight transposes + spikes convert, 1 dispatch
    prep_k<<<3376, 256, 0, stream>>>(
        spikes, embed_w, proj_w, Wq, Wk, Wv, Wo, up_w, down_w,
        spbf, embT, projT, qkvT, woT, upT, downT);

    // ---- embedding ----
    mm64_k<1, 0, 1, 0><<<dim3(D_ / 64, M / 64), 256, 0, stream>>>(
        spbf, embT, embed_b, nullptr, nullptr, nullptr,
        tbf, nullptr, nullptr, M, D_, C_);
    mm64_k<0, 0, 0, 0><<<dim3(H_ / 64, M / 64), 256, 0, stream>>>(
        tbf, projT, proj_b, nullptr, nullptr, nullptr,
        x, nullptr, nullptr, M, H_, D_);

    for (int l = 0; l < L_; ++l) {
        const unsigned short* qkvT_l = qkvT + (size_t)l * 3 * H_ * H_;
        const unsigned short* woT_l  = woT  + (size_t)l * H_ * H_;
        const unsigned short* upT_l  = upT  + (size_t)l * INTER_ * H_;
        const unsigned short* dnT_l  = downT + (size_t)l * H_ * INTER_;

        ln_k<<<M, 256, 0, stream>>>(x, ln1_g + l * H_, ln1_b + l * H_, hbf);

        // fused QKV + bias (+0.125 q scale) -> qb, kb, vb (bf16 [M,512])
        // 128x64 tile: grid 24x32 = 768 blocks = 3 blocks/CU
        mm128_k<0, 0, 1, 1><<<dim3((3 * H_) / 64, M / 128), 256, 0, stream>>>(
            hbf, qkvT_l, bq + l * H_, bk + l * H_, bv + l * H_, nullptr,
            qb, kb, vb, M, 3 * H_, H_);

        // attention (RoPE fused; Q in registers; 3 blocks/CU)
        attn_k<<<B_ * NH_ * (T_ / 64), 256, 0, stream>>>(qb, kb, vb, smask, ts, obf);

        // x = x + obuf @ Wo + bo  (64x64 BK=128: grid 512 = 2 blocks/CU)
        mm64_k<0, 1, 0, 0><<<dim3(H_ / 64, M / 64), 256, 0, stream>>>(
            obf, woT_l, bo + l * H_, nullptr, nullptr, x,
            x, nullptr, nullptr, M, H_, H_);

        ln_k<<<M, 256, 0, stream>>>(x, ln2_g + l * H_, ln2_b + l * H_, hbf);

        // inter = gelu(h @ up_w + b)  (128x64: grid 32x32 = 1024 blocks)
        mm128_k<1, 0, 1, 0><<<dim3(INTER_ / 64, M / 128), 256, 0, stream>>>(
            hbf, upT_l, up_b + l * INTER_, nullptr, nullptr, nullptr,
            ibf, nullptr, nullptr, M, INTER_, H_);

        // x = x + inter @ down_w + b  (64x64 BK=128: 16 drains instead of 32)
        float* dst = (l == L_ - 1) ? (float*)d_out : x;
        mm64_k<0, 1, 0, 0><<<dim3(H_ / 64, M / 64), 256, 0, stream>>>(
            ibf, dnT_l, down_b + l * H_, nullptr, nullptr, x,
            dst, nullptr, nullptr, M, H_, INTER_);
    }
}

// Round 6
// 493.833 us; speedup vs baseline: 1.1379x; 1.0083x over previous
//
#include <hip/hip_runtime.h>
#include <math.h>

// Problem dims (fixed)
#define B_ 4
#define T_ 1024
#define C_ 256
#define D_ 256
#define H_ 512
#define NH_ 8
#define HD_ 64
#define INTER_ 2048
#define L_ 4
#define CB_ 128   // context_backward; context_forward = 0

typedef short bf16x8 __attribute__((ext_vector_type(8)));
typedef unsigned short ush8 __attribute__((ext_vector_type(8)));
typedef float f32x4 __attribute__((ext_vector_type(4)));

__device__ __forceinline__ float gelu_exact(float x) {
    return 0.5f * x * (1.0f + erff(x * 0.70710678118654752f));
}

// fp32 -> bf16 round-to-nearest-even
__device__ __forceinline__ unsigned short f2bf(float f) {
    unsigned u = __float_as_uint(f);
    u += 0x7fffu + ((u >> 16) & 1u);
    return (unsigned short)(u >> 16);
}
__device__ __forceinline__ float bf2f(unsigned short h) {
    return __uint_as_float((unsigned)h << 16);
}

// XCD-chunked bijective block swizzle (T1). Requires nwg % 8 == 0.
__device__ __forceinline__ void xcd_swz(int& bx, int& by) {
    const int gx  = gridDim.x;
    const int nwg = gx * gridDim.y;
    int bid = blockIdx.y * gx + blockIdx.x;
    bid = (bid & 7) * (nwg >> 3) + (bid >> 3);
    bx = bid % gx;
    by = bid / gx;
}

// ---------------------------------------------------------------------------
// bf16 MFMA GEMM, 64x64 tile, BK=256, XOR-swizzled LDS. The lever that has
// worked twice (R2->R5): FEWER full vmcnt(0)+barrier drains. down K=2048:
// 8 drains (was 16 at BK=128, 32 at BK=64), 32 MFMAs amortize each. Swizzle
// unchanged: row stride (512B) = 0 mod 128B so chunk g ^ (row&7) still gives
// 2 lanes/bank (free). Same per-lane k-order -> bit-identical results.
// LDS 64 KB -> 2 blocks/CU, which is all these grid-512 launches can use.
// ---------------------------------------------------------------------------
template<int ACT, int RES, int OBF, int SPLIT>
__global__ __launch_bounds__(256) void mm64_k(
    const unsigned short* __restrict__ A, const unsigned short* __restrict__ BT,
    const float* __restrict__ b0, const float* __restrict__ b1,
    const float* __restrict__ b2,
    const float* res,
    void* o0, void* o1, void* o2,
    const int M, const int N, const int K)
{
    __shared__ unsigned short As[64 * 256];
    __shared__ unsigned short Bs[64 * 256];

    int bx, by; xcd_swz(bx, by);

    const int tid  = threadIdx.x;
    const int lane = tid & 63;
    const int w    = tid >> 6;
    const int m0   = by * 64;
    const int n0   = bx * 64;
    const int wm   = (w >> 1) * 32;
    const int wn   = (w & 1) * 32;
    const int l16  = lane & 15;
    const int g16  = lane >> 4;

    f32x4 acc[2][2] = {};

    const unsigned short* Abase = A  + (size_t)m0 * K;
    const unsigned short* Bbase = BT + (size_t)n0 * K;

    for (int k0 = 0; k0 < K; k0 += 256) {
        __syncthreads();                 // LDS reuse guard
        // 64 rows x 256 cols = 2048 16B-chunks per tile, 8 issues/thread each
#pragma unroll
        for (int it = 0; it < 8; ++it) {
            const int c  = it * 256 + tid;
            const int rc = c >> 5;                    // row 0..63 (32 chunks/row)
            const int gk = (c & 31) ^ (rc & 7);       // swizzled k-group
            __builtin_amdgcn_global_load_lds(
                (const __attribute__((address_space(1))) unsigned*)(Abase + (size_t)rc * K + k0 + gk * 8),
                (__attribute__((address_space(3))) unsigned*)(As + (size_t)(it * 256 + (w << 6)) * 8), 16, 0, 0);
        }
#pragma unroll
        for (int it = 0; it < 8; ++it) {
            const int c  = it * 256 + tid;
            const int rc = c >> 5;
            const int gk = (c & 31) ^ (rc & 7);
            __builtin_amdgcn_global_load_lds(
                (const __attribute__((address_space(1))) unsigned*)(Bbase + (size_t)rc * K + k0 + gk * 8),
                (__attribute__((address_space(3))) unsigned*)(Bs + (size_t)(it * 256 + (w << 6)) * 8), 16, 0, 0);
        }
        __syncthreads();                 // implicit vmcnt(0): tile landed

#pragma unroll
        for (int kk = 0; kk < 8; ++kk) {
            const int kf = kk * 4 + g16;            // k-group 0..31
            const int sw = (kf ^ (l16 & 7)) * 8;    // swizzled ushort offset
            bf16x8 a[2], b[2];
#pragma unroll
            for (int t = 0; t < 2; ++t)
                a[t] = *(const bf16x8*)&As[(wm + t * 16 + l16) * 256 + sw];
#pragma unroll
            for (int t = 0; t < 2; ++t)
                b[t] = *(const bf16x8*)&Bs[(wn + t * 16 + l16) * 256 + sw];
#pragma unroll
            for (int i = 0; i < 2; ++i)
#pragma unroll
                for (int j = 0; j < 2; ++j)
                    acc[i][j] = __builtin_amdgcn_mfma_f32_16x16x32_bf16(a[i], b[j], acc[i][j], 0, 0, 0);
        }
    }

    if (OBF || SPLIT) {
        __syncthreads();
        unsigned short* Eb = ((w < 2) ? As : Bs) + (w & 1) * 1024;
        const int row16 = lane >> 2;
        const int cg    = lane & 3;

        const int gnb   = n0 + wn;
        const int which = SPLIT ? (gnb >> 9) : 0;
        const int lnb   = SPLIT ? (gnb & 511) : gnb;
        const int ldo   = SPLIT ? 512 : N;
        unsigned short* oo = SPLIT
            ? ((which == 0) ? (unsigned short*)o0 : (which == 1) ? (unsigned short*)o1 : (unsigned short*)o2)
            : (unsigned short*)o0;
        const float* bb = SPLIT ? ((which == 0) ? b0 : (which == 1) ? b1 : b2) : b0;
        const float scale = (SPLIT && which == 0) ? 0.125f : 1.0f;

#pragma unroll
        for (int i = 0; i < 2; ++i) {
#pragma unroll
            for (int j = 0; j < 2; ++j) {
                const float bv = bb[lnb + j * 16 + l16];
#pragma unroll
                for (int r = 0; r < 4; ++r) {
                    float cv = acc[i][j][r] + bv;
                    if (ACT) cv = gelu_exact(cv);
                    if (SPLIT) cv *= scale;
                    Eb[(g16 * 4 + r) * 40 + j * 16 + l16] = f2bf(cv);
                }
            }
            const int grow0 = m0 + wm + i * 16 + row16;
#pragma unroll
            for (int s = 0; s < 2; ++s) {
                ushort4 t4 = *(const ushort4*)&Eb[row16 * 40 + s * 16 + cg * 4];
                *(ushort4*)&oo[(size_t)grow0 * ldo + lnb + s * 16 + cg * 4] = t4;
            }
        }
        return;
    }

    // fp32 out epilogue (scalar 4B stores = full 64B runs per 16 lanes)
#pragma unroll
    for (int i = 0; i < 2; ++i) {
        const int gmb = m0 + wm + i * 16 + g16 * 4;
#pragma unroll
        for (int j = 0; j < 2; ++j) {
            const int gn = n0 + wn + j * 16 + l16;
            const float bv = b0[gn];
#pragma unroll
            for (int r = 0; r < 4; ++r) {
                float cv = acc[i][j][r] + bv;
                if (ACT) cv = gelu_exact(cv);
                if (RES) cv += res[(size_t)(gmb + r) * 512 + gn];
                ((float*)o0)[(size_t)(gmb + r) * N + gn] = cv;
            }
        }
    }
}

// ---------------------------------------------------------------------------
// bf16 MFMA GEMM, 128xBN tile, BK=128. BN=64 (QKV: 48KB LDS, 3 blocks/CU,
// grid 768) or BN=128 (up: 64KB LDS, 2 blocks/CU, grid 512 -- NOT R1's
// 1-block/CU collapse). K=512 -> 4 drains (was 8).
// ---------------------------------------------------------------------------
template<int ACT, int RES, int OBF, int SPLIT, int BN>
__global__ __launch_bounds__(256) void mm128_k(
    const unsigned short* __restrict__ A, const unsigned short* __restrict__ BT,
    const float* __restrict__ b0, const float* __restrict__ b1,
    const float* __restrict__ b2,
    const float* res,
    void* o0, void* o1, void* o2,
    const int M, const int N, const int K)
{
    constexpr int NJ = BN / 32;           // j-frags per wave (2 or 4)

    __shared__ unsigned short As[128 * 128];
    __shared__ unsigned short Bs[BN * 128];

    int bx, by; xcd_swz(bx, by);

    const int tid  = threadIdx.x;
    const int lane = tid & 63;
    const int w    = tid >> 6;
    const int m0   = by * 128;
    const int n0   = bx * BN;
    const int wm   = (w >> 1) * 64;       // 0 or 64
    const int wn   = (w & 1) * (BN / 2);
    const int l16  = lane & 15;
    const int g16  = lane >> 4;

    f32x4 acc[4][NJ] = {};

    const unsigned short* Abase = A  + (size_t)m0 * K;
    const unsigned short* Bbase = BT + (size_t)n0 * K;

    for (int k0 = 0; k0 < K; k0 += 128) {
        __syncthreads();
        // A: 128 rows x 128 cols = 2048 chunks, 8 issues/thread
#pragma unroll
        for (int it = 0; it < 8; ++it) {
            const int c  = it * 256 + tid;
            const int rc = c >> 4;                    // 16 chunks/row
            const int gk = (c & 15) ^ (rc & 7);
            __builtin_amdgcn_global_load_lds(
                (const __attribute__((address_space(1))) unsigned*)(Abase + (size_t)rc * K + k0 + gk * 8),
                (__attribute__((address_space(3))) unsigned*)(As + (size_t)(it * 256 + (w << 6)) * 8), 16, 0, 0);
        }
        // B: BN rows x 128 cols, NJ*2 issues/thread
#pragma unroll
        for (int it = 0; it < NJ * 2; ++it) {
            const int c  = it * 256 + tid;
            const int rc = c >> 4;
            const int gk = (c & 15) ^ (rc & 7);
            __builtin_amdgcn_global_load_lds(
                (const __attribute__((address_space(1))) unsigned*)(Bbase + (size_t)rc * K + k0 + gk * 8),
                (__attribute__((address_space(3))) unsigned*)(Bs + (size_t)(it * 256 + (w << 6)) * 8), 16, 0, 0);
        }
        __syncthreads();

#pragma unroll
        for (int kk = 0; kk < 4; ++kk) {
            const int kf = kk * 4 + g16;            // k-group 0..15
            const int sw = (kf ^ (l16 & 7)) * 8;    // swizzled ushort offset
            bf16x8 a[4], b[NJ];
#pragma unroll
            for (int t = 0; t < 4; ++t)
                a[t] = *(const bf16x8*)&As[(wm + t * 16 + l16) * 128 + sw];
#pragma unroll
            for (int t = 0; t < NJ; ++t)
                b[t] = *(const bf16x8*)&Bs[(wn + t * 16 + l16) * 128 + sw];
#pragma unroll
            for (int i = 0; i < 4; ++i)
#pragma unroll
                for (int j = 0; j < NJ; ++j)
                    acc[i][j] = __builtin_amdgcn_mfma_f32_16x16x32_bf16(a[i], b[j], acc[i][j], 0, 0, 0);
        }
    }

    if (OBF || SPLIT) {
        __syncthreads();
        constexpr int WC  = NJ * 16;          // wave cols (32 or 64)
        constexpr int EST = WC + 8;           // Eb stride (pad breaks conflicts)
        constexpr int LPR = WC / 4;           // lanes per row in store
        constexpr int RPI = 64 / LPR;         // rows per store instruction
        unsigned short* Eb = As + w * (16 * EST);
        const int erow = lane / LPR;
        const int ecol = (lane % LPR) * 4;

        const int gnb   = n0 + wn;
        const int which = SPLIT ? (gnb >> 9) : 0;
        const int lnb   = SPLIT ? (gnb & 511) : gnb;
        const int ldo   = SPLIT ? 512 : N;
        unsigned short* oo = SPLIT
            ? ((which == 0) ? (unsigned short*)o0 : (which == 1) ? (unsigned short*)o1 : (unsigned short*)o2)
            : (unsigned short*)o0;
        const float* bb = SPLIT ? ((which == 0) ? b0 : (which == 1) ? b1 : b2) : b0;
        const float scale = (SPLIT && which == 0) ? 0.125f : 1.0f;

#pragma unroll
        for (int i = 0; i < 4; ++i) {
#pragma unroll
            for (int j = 0; j < NJ; ++j) {
                const float bv = bb[lnb + j * 16 + l16];
#pragma unroll
                for (int r = 0; r < 4; ++r) {
                    float cv = acc[i][j][r] + bv;
                    if (ACT) cv = gelu_exact(cv);
                    if (SPLIT) cv *= scale;
                    Eb[(g16 * 4 + r) * EST + j * 16 + l16] = f2bf(cv);
                }
            }
            const int grow0 = m0 + wm + i * 16;
#pragma unroll
            for (int s = 0; s < NJ; ++s) {
                ushort4 t4 = *(const ushort4*)&Eb[(s * RPI + erow) * EST + ecol];
                *(ushort4*)&oo[(size_t)(grow0 + s * RPI + erow) * ldo + lnb + ecol] = t4;
            }
        }
        return;
    }

    // fp32 out epilogue
#pragma unroll
    for (int i = 0; i < 4; ++i) {
        const int gmb = m0 + wm + i * 16 + g16 * 4;
#pragma unroll
        for (int j = 0; j < NJ; ++j) {
            const int gn = n0 + wn + j * 16 + l16;
            const float bv = b0[gn];
#pragma unroll
            for (int r = 0; r < 4; ++r) {
                float cv = acc[i][j][r] + bv;
                if (ACT) cv = gelu_exact(cv);
                if (RES) cv += res[(size_t)(gmb + r) * 512 + gn];
                ((float*)o0)[(size_t)(gmb + r) * N + gn] = cv;
            }
        }
    }
}

// ---------------------------------------------------------------------------
// Fused prologue: ONE dispatch for all weight transposes + spikes convert.
// ---------------------------------------------------------------------------
__global__ __launch_bounds__(256) void prep_k(
    const float* __restrict__ spikes,
    const float* __restrict__ embed_w, const float* __restrict__ proj_w,
    const float* __restrict__ Wq, const float* __restrict__ Wk,
    const float* __restrict__ Wv, const float* __restrict__ Wo,
    const float* __restrict__ up_w, const float* __restrict__ down_w,
    unsigned short* __restrict__ spbf,
    unsigned short* __restrict__ embT, unsigned short* __restrict__ projT,
    unsigned short* __restrict__ qkvT, unsigned short* __restrict__ woT,
    unsigned short* __restrict__ upT, unsigned short* __restrict__ downT)
{
    const int idx = blockIdx.x;
    const int tid = threadIdx.x;

    if (idx >= 3120) {  // spikes fp32->bf16: 256 blocks x 4096 elems
        const int base = (idx - 3120) * 4096 + tid * 16;
#pragma unroll
        for (int s = 0; s < 4; ++s) {
            float4 v = *(const float4*)&spikes[base + s * 4];
            ushort4 o = {f2bf(v.x), f2bf(v.y), f2bf(v.z), f2bf(v.w)};
            *(ushort4*)&spbf[base + s * 4] = o;
        }
        return;
    }

    const float* src; unsigned short* dst; int R, Cc, t;
    if (idx < 16)      { src = embed_w; dst = embT;  R = C_; Cc = D_; t = idx; }
    else if (idx < 48) { src = proj_w;  dst = projT; R = D_; Cc = H_; t = idx - 16; }
    else if (idx < 816) {
        const int j = idx - 48;        // 0..767: Wq | Wk | Wv, 4 layers x 64 tiles
        const int wsel = j >> 8;
        const int l = (j & 255) >> 6;
        t = j & 63;
        src = ((wsel == 0) ? Wq : (wsel == 1) ? Wk : Wv) + (size_t)l * H_ * H_;
        dst = qkvT + (size_t)l * 3 * H_ * H_ + (size_t)wsel * H_ * H_;
        R = H_; Cc = H_;
    } else if (idx < 1072) {
        const int j = idx - 816; const int l = j >> 6; t = j & 63;
        src = Wo + (size_t)l * H_ * H_; dst = woT + (size_t)l * H_ * H_;
        R = H_; Cc = H_;
    } else if (idx < 2096) {
        const int j = idx - 1072; const int l = j >> 8; t = j & 255;
        src = up_w + (size_t)l * H_ * INTER_; dst = upT + (size_t)l * INTER_ * H_;
        R = H_; Cc = INTER_;
    } else {
        const int j = idx - 2096; const int l = j >> 8; t = j & 255;
        src = down_w + (size_t)l * INTER_ * H_; dst = downT + (size_t)l * H_ * INTER_;
        R = INTER_; Cc = H_;
    }
    const int ntx = Cc >> 6;
    const int c0 = (t % ntx) * 64, r0 = (t / ntx) * 64;

    __shared__ float tile[64][65];
    const int tr = tid >> 4, tc = (tid & 15) * 4;
#pragma unroll
    for (int i = 0; i < 4; ++i) {
        float4 v = *(const float4*)&src[(size_t)(r0 + tr + i * 16) * Cc + c0 + tc];
        tile[tr + i * 16][tc + 0] = v.x;
        tile[tr + i * 16][tc + 1] = v.y;
        tile[tr + i * 16][tc + 2] = v.z;
        tile[tr + i * 16][tc + 3] = v.w;
    }
    __syncthreads();
#pragma unroll
    for (int i = 0; i < 4; ++i) {
        const int n = tr + i * 16;
        ushort4 o;
        o.x = f2bf(tile[tc + 0][n]);
        o.y = f2bf(tile[tc + 1][n]);
        o.z = f2bf(tile[tc + 2][n]);
        o.w = f2bf(tile[tc + 3][n]);
        *(ushort4*)&dst[(size_t)(c0 + n) * R + r0 + tc] = o;
    }
}

// ---------------------------------------------------------------------------
// LayerNorm over H=512, bf16 output.
// ---------------------------------------------------------------------------
__global__ __launch_bounds__(256) void ln_k(
    const float* __restrict__ x, const float* __restrict__ g,
    const float* __restrict__ b, unsigned short* __restrict__ out)
{
    const int row = blockIdx.x;
    const int tid = threadIdx.x;
    const float* xr = x + (size_t)row * H_;

    float v0 = xr[tid];
    float v1 = xr[tid + 256];

    float s = v0 + v1;
#pragma unroll
    for (int off = 32; off; off >>= 1) s += __shfl_xor(s, off);

    __shared__ float red[4];
    const int wave = tid >> 6;
    if ((tid & 63) == 0) red[wave] = s;
    __syncthreads();
    const float mean = (red[0] + red[1] + red[2] + red[3]) * (1.0f / (float)H_);

    const float d0 = v0 - mean, d1 = v1 - mean;
    float q = d0 * d0 + d1 * d1;
#pragma unroll
    for (int off = 32; off; off >>= 1) q += __shfl_xor(q, off);
    __syncthreads();
    if ((tid & 63) == 0) red[wave] = q;
    __syncthreads();
    const float var = (red[0] + red[1] + red[2] + red[3]) * (1.0f / (float)H_);
    const float rstd = rsqrtf(var + 1e-5f);

    out[(size_t)row * H_ + tid]       = f2bf(d0 * rstd * g[tid] + b[tid]);
    out[(size_t)row * H_ + tid + 256] = f2bf(d1 * rstd * g[tid + 256] + b[tid + 256]);
}

// ---------------------------------------------------------------------------
// MFMA banded attention. RoPE'd Q built in registers (R5-proven); LDS 52 KB
// -> 3 blocks/CU.
// ---------------------------------------------------------------------------
#define AWIN 192
#define AKS 72
#define AVS 200

__global__ __launch_bounds__(256) void attn_k(
    const unsigned short* __restrict__ q, const unsigned short* __restrict__ k,
    const unsigned short* __restrict__ v, const int* __restrict__ smask,
    const int* __restrict__ ts, unsigned short* __restrict__ o)
{
    __shared__ unsigned short Ks[AWIN * AKS];   // reused as Pb after S-pass
    __shared__ unsigned short Vt[64 * AVS];
    unsigned short* const Pb = Ks;              // 64*AVS = 12800 <= 13824

    const int blk = blockIdx.x;
    const int qt = blk & 15;
    const int h  = (blk >> 4) & 7;
    const int b  = blk >> 7;
    const int tid  = threadIdx.x;
    const int lane = tid & 63;
    const int w    = tid >> 6;
    const int l16  = lane & 15;
    const int g16  = lane >> 4;

    const int qlo = qt * 64;
    const int klo = (qlo >= CB_) ? (qlo - CB_) : 0;
    const int tb  = b * 1024;

    // ---- Q with RoPE, straight into the a-frag registers ----
    bf16x8 qa0, qa1;
    {
        const int qrow = w * 16 + l16;
        const unsigned short* gq = q + ((size_t)(tb + qlo + qrow)) * 512 + h * 64;
        ush8 lo = *(const ush8*)&gq[g16 * 8];
        ush8 hi = *(const ush8*)&gq[g16 * 8 + 32];
        const float tstamp = (float)ts[tb + qlo + qrow];
#pragma unroll
        for (int j = 0; j < 8; ++j) {
            const int d = g16 * 8 + j;
            const float freq = __expf(-0.2878231366242558f * (float)d);
            const float ang = tstamp * freq;
            const float cc = __cosf(ang), ss = __sinf(ang);
            const float v1 = bf2f(lo[j]);
            const float v2 = bf2f(hi[j]);
            ((unsigned short*)&qa0)[j] = f2bf(v1 * cc - v2 * ss);
            ((unsigned short*)&qa1)[j] = f2bf(v2 * cc + v1 * ss);
        }
    }

    // ---- stage K with RoPE ----
    {
        const unsigned short* gk = k + ((size_t)(tb + klo)) * 512 + h * 64;
        for (int c = tid; c < AWIN * 8; c += 256) {
            const int row = c >> 3, c4 = (c & 7) * 4;
            ushort4 lo = *(const ushort4*)&gk[(size_t)row * 512 + c4];
            ushort4 hi = *(const ushort4*)&gk[(size_t)row * 512 + c4 + 32];
            const float tstamp = (float)ts[tb + klo + row];
            ushort4 olo, ohi;
#pragma unroll
            for (int j2 = 0; j2 < 4; ++j2) {
                const float freq = __expf(-0.2878231366242558f * (float)(c4 + j2));
                const float ang = tstamp * freq;
                const float cc = __cosf(ang), ss = __sinf(ang);
                const float v1 = bf2f(((const unsigned short*)&lo)[j2]);
                const float v2 = bf2f(((const unsigned short*)&hi)[j2]);
                ((unsigned short*)&olo)[j2] = f2bf(v1 * cc - v2 * ss);
                ((unsigned short*)&ohi)[j2] = f2bf(v2 * cc + v1 * ss);
            }
            *(ushort4*)&Ks[row * AKS + c4]      = olo;
            *(ushort4*)&Ks[row * AKS + c4 + 32] = ohi;
        }
    }
    // ---- stage V (transposed into LDS) ----
    {
        const unsigned short* gv = v + ((size_t)(tb + klo)) * 512 + h * 64;
        for (int c = tid; c < AWIN * 16; c += 256) {
            const int row = c >> 4, c4 = (c & 15) * 4;
            ushort4 vv = *(const ushort4*)&gv[(size_t)row * 512 + c4];
            Vt[(c4 + 0) * AVS + row] = vv.x;
            Vt[(c4 + 1) * AVS + row] = vv.y;
            Vt[(c4 + 2) * AVS + row] = vv.z;
            Vt[(c4 + 3) * AVS + row] = vv.w;
        }
    }
    __syncthreads();

    // ---- S = Q @ K^T ----
    f32x4 accs[12];
#pragma unroll
    for (int t = 0; t < 12; ++t) {
        const bf16x8 b0 = *(const bf16x8*)&Ks[(t * 16 + l16) * AKS + g16 * 8];
        const bf16x8 b1 = *(const bf16x8*)&Ks[(t * 16 + l16) * AKS + 32 + g16 * 8];
        f32x4 c = {};
        c = __builtin_amdgcn_mfma_f32_16x16x32_bf16(qa0, b0, c, 0, 0, 0);
        c = __builtin_amdgcn_mfma_f32_16x16x32_bf16(qa1, b1, c, 0, 0, 0);
        accs[t] = c;
    }

    // ---- softmax in registers ----
    bool mk[12];
    int  jj[12];
#pragma unroll
    for (int t = 0; t < 12; ++t) {
        jj[t] = klo + t * 16 + l16;
        mk[t] = smask[tb + jj[t]] > 0;
    }

    float rs[4];
#pragma unroll
    for (int r = 0; r < 4; ++r) {
        const int i = qlo + 16 * w + g16 * 4 + r;
        float mx = -1e30f;
#pragma unroll
        for (int t = 0; t < 12; ++t) {
            const bool val = mk[t] && (jj[t] >= i - CB_) && (jj[t] <= i);
            mx = fmaxf(mx, val ? accs[t][r] : -1e30f);
        }
        mx = fmaxf(mx, __shfl_xor(mx, 1));
        mx = fmaxf(mx, __shfl_xor(mx, 2));
        mx = fmaxf(mx, __shfl_xor(mx, 4));
        mx = fmaxf(mx, __shfl_xor(mx, 8));
        float sum = 0.0f;
#pragma unroll
        for (int t = 0; t < 12; ++t) {
            const bool val = mk[t] && (jj[t] >= i - CB_) && (jj[t] <= i);
            const float p = val ? __expf(accs[t][r] - mx) : 0.0f;
            accs[t][r] = p;
            sum += p;
        }
        sum += __shfl_xor(sum, 1);
        sum += __shfl_xor(sum, 2);
        sum += __shfl_xor(sum, 4);
        sum += __shfl_xor(sum, 8);
        rs[r] = 1.0f / sum;
    }

    // Ks dead from here; Pb aliases it.
    __syncthreads();

    // ---- P -> LDS ----
#pragma unroll
    for (int t = 0; t < 12; ++t)
#pragma unroll
        for (int r = 0; r < 4; ++r)
            Pb[(16 * w + g16 * 4 + r) * AVS + t * 16 + l16] = f2bf(accs[t][r]);

    // ---- O = P @ V ----
    f32x4 acco[4];
#pragma unroll
    for (int nt = 0; nt < 4; ++nt) {
        f32x4 c = {};
#pragma unroll
        for (int ks = 0; ks < 6; ++ks) {
            const bf16x8 a = *(const bf16x8*)&Pb[(16 * w + l16) * AVS + ks * 32 + g16 * 8];
            const bf16x8 bb = *(const bf16x8*)&Vt[(nt * 16 + l16) * AVS + ks * 32 + g16 * 8];
            c = __builtin_amdgcn_mfma_f32_16x16x32_bf16(a, bb, c, 0, 0, 0);
        }
        acco[nt] = c;
    }

    // ---- stage O into Pb, vector store ----
    __syncthreads();
#pragma unroll
    for (int nt = 0; nt < 4; ++nt)
#pragma unroll
        for (int r = 0; r < 4; ++r)
            Pb[(16 * w + g16 * 4 + r) * AVS + nt * 16 + l16] = f2bf(acco[nt][r] * rs[r]);

    const int row16 = lane >> 2, cg = lane & 3;
    const int grow = tb + qlo + 16 * w + row16;
#pragma unroll
    for (int s = 0; s < 4; ++s) {
        ushort4 t4 = *(const ushort4*)&Pb[(16 * w + row16) * AVS + s * 16 + cg * 4];
        *(ushort4*)&o[(size_t)grow * 512 + h * 64 + s * 16 + cg * 4] = t4;
    }
}

// ---------------------------------------------------------------------------
extern "C" void kernel_launch(void* const* d_in, const int* in_sizes, int n_in,
                              void* d_out, int out_size, void* d_ws, size_t ws_size,
                              hipStream_t stream)
{
    const float* spikes  = (const float*)d_in[0];
    const int*   smask   = (const int*)d_in[1];
    const int*   ts      = (const int*)d_in[2];
    const float* embed_w = (const float*)d_in[3];
    const float* embed_b = (const float*)d_in[4];
    const float* proj_w  = (const float*)d_in[5];
    const float* proj_b  = (const float*)d_in[6];
    const float* ln1_g   = (const float*)d_in[7];
    const float* ln1_b   = (const float*)d_in[8];
    const float* Wq      = (const float*)d_in[9];
    const float* bq      = (const float*)d_in[10];
    const float* Wk      = (const float*)d_in[11];
    const float* bk      = (const float*)d_in[12];
    const float* Wv      = (const float*)d_in[13];
    const float* bv      = (const float*)d_in[14];
    const float* Wo      = (const float*)d_in[15];
    const float* bo      = (const float*)d_in[16];
    const float* ln2_g   = (const float*)d_in[17];
    const float* ln2_b   = (const float*)d_in[18];
    const float* up_w    = (const float*)d_in[19];
    const float* up_b    = (const float*)d_in[20];
    const float* down_w  = (const float*)d_in[21];
    const float* down_b  = (const float*)d_in[22];

    const int M = B_ * T_;  // 4096

    char* p = (char*)d_ws;
    float* x = (float*)p;                       p += (size_t)M * H_ * 4;
    unsigned short* qb  = (unsigned short*)p;   p += (size_t)M * H_ * 2;
    unsigned short* kb  = (unsigned short*)p;   p += (size_t)M * H_ * 2;
    unsigned short* vb  = (unsigned short*)p;   p += (size_t)M * H_ * 2;
    unsigned short* hbf = (unsigned short*)p;   p += (size_t)M * H_ * 2;
    unsigned short* obf = (unsigned short*)p;   p += (size_t)M * H_ * 2;
    unsigned short* ibf = (unsigned short*)p;   p += (size_t)M * INTER_ * 2;
    unsigned short* tbf = (unsigned short*)p;   p += (size_t)M * D_ * 2;
    unsigned short* spbf  = (unsigned short*)p; p += (size_t)M * C_ * 2;
    unsigned short* embT  = (unsigned short*)p; p += (size_t)D_ * C_ * 2;
    unsigned short* projT = (unsigned short*)p; p += (size_t)H_ * D_ * 2;
    unsigned short* qkvT  = (unsigned short*)p; p += (size_t)L_ * 3 * H_ * H_ * 2;
    unsigned short* woT   = (unsigned short*)p; p += (size_t)L_ * H_ * H_ * 2;
    unsigned short* upT   = (unsigned short*)p; p += (size_t)L_ * INTER_ * H_ * 2;
    unsigned short* downT = (unsigned short*)p; p += (size_t)L_ * H_ * INTER_ * 2;

    // ---- fused prologue: all weight transposes + spikes convert, 1 dispatch
    prep_k<<<3376, 256, 0, stream>>>(
        spikes, embed_w, proj_w, Wq, Wk, Wv, Wo, up_w, down_w,
        spbf, embT, projT, qkvT, woT, upT, downT);

    // ---- embedding ----  (K=256: single drain per tile)
    mm64_k<1, 0, 1, 0><<<dim3(D_ / 64, M / 64), 256, 0, stream>>>(
        spbf, embT, embed_b, nullptr, nullptr, nullptr,
        tbf, nullptr, nullptr, M, D_, C_);
    mm64_k<0, 0, 0, 0><<<dim3(H_ / 64, M / 64), 256, 0, stream>>>(
        tbf, projT, proj_b, nullptr, nullptr, nullptr,
        x, nullptr, nullptr, M, H_, D_);

    for (int l = 0; l < L_; ++l) {
        const unsigned short* qkvT_l = qkvT + (size_t)l * 3 * H_ * H_;
        const unsigned short* woT_l  = woT  + (size_t)l * H_ * H_;
        const unsigned short* upT_l  = upT  + (size_t)l * INTER_ * H_;
        const unsigned short* dnT_l  = downT + (size_t)l * H_ * INTER_;

        ln_k<<<M, 256, 0, stream>>>(x, ln1_g + l * H_, ln1_b + l * H_, hbf);

        // fused QKV + bias (+0.125 q scale): 128x64 BK=128, grid 768, 4 drains
        mm128_k<0, 0, 1, 1, 64><<<dim3((3 * H_) / 64, M / 128), 256, 0, stream>>>(
            hbf, qkvT_l, bq + l * H_, bk + l * H_, bv + l * H_, nullptr,
            qb, kb, vb, M, 3 * H_, H_);

        // attention (RoPE fused; Q in registers; 3 blocks/CU)
        attn_k<<<B_ * NH_ * (T_ / 64), 256, 0, stream>>>(qb, kb, vb, smask, ts, obf);

        // x = x + obuf @ Wo + bo  (64x64 BK=256: 2 drains)
        mm64_k<0, 1, 0, 0><<<dim3(H_ / 64, M / 64), 256, 0, stream>>>(
            obf, woT_l, bo + l * H_, nullptr, nullptr, x,
            x, nullptr, nullptr, M, H_, H_);

        ln_k<<<M, 256, 0, stream>>>(x, ln2_g + l * H_, ln2_b + l * H_, hbf);

        // inter = gelu(h @ up_w + b)  (128x128 BK=128: grid 512 = 2/CU, 4 drains)
        mm128_k<1, 0, 1, 0, 128><<<dim3(INTER_ / 128, M / 128), 256, 0, stream>>>(
            hbf, upT_l, up_b + l * INTER_, nullptr, nullptr, nullptr,
            ibf, nullptr, nullptr, M, INTER_, H_);

        // x = x + inter @ down_w + b  (64x64 BK=256: 8 drains)
        float* dst = (l == L_ - 1) ? (float*)d_out : x;
        mm64_k<0, 1, 0, 0><<<dim3(H_ / 64, M / 64), 256, 0, stream>>>(
            ibf, dnT_l, down_b + l * H_, nullptr, nullptr, x,
            dst, nullptr, nullptr, M, H_, INTER_);
    }
}

// Round 7
// 482.103 us; speedup vs baseline: 1.1656x; 1.0243x over previous
//
#include <hip/hip_runtime.h>
#include <math.h>

// Problem dims (fixed)
#define B_ 4
#define T_ 1024
#define C_ 256
#define D_ 256
#define H_ 512
#define NH_ 8
#define HD_ 64
#define INTER_ 2048
#define L_ 4
#define CB_ 128   // context_backward; context_forward = 0

typedef short bf16x8 __attribute__((ext_vector_type(8)));
typedef unsigned short ush8 __attribute__((ext_vector_type(8)));
typedef float f32x4 __attribute__((ext_vector_type(4)));

__device__ __forceinline__ float gelu_exact(float x) {
    return 0.5f * x * (1.0f + erff(x * 0.70710678118654752f));
}

// fp32 -> bf16 round-to-nearest-even
__device__ __forceinline__ unsigned short f2bf(float f) {
    unsigned u = __float_as_uint(f);
    u += 0x7fffu + ((u >> 16) & 1u);
    return (unsigned short)(u >> 16);
}
__device__ __forceinline__ float bf2f(unsigned short h) {
    return __uint_as_float((unsigned)h << 16);
}

// XCD-chunked bijective block swizzle (T1). Requires nwg % 8 == 0.
__device__ __forceinline__ void xcd_swz(int& bx, int& by) {
    const int gx  = gridDim.x;
    const int nwg = gx * gridDim.y;
    int bid = blockIdx.y * gx + blockIdx.x;
    bid = (bid & 7) * (nwg >> 3) + (bid >> 3);
    bx = bid % gx;
    by = bid / gx;
}

// ---------------------------------------------------------------------------
// bf16 MFMA GEMM, 64x64 tile, BK=256, XOR-swizzled LDS (R6-proven).
// ---------------------------------------------------------------------------
template<int ACT, int RES, int OBF, int SPLIT>
__global__ __launch_bounds__(256) void mm64_k(
    const unsigned short* __restrict__ A, const unsigned short* __restrict__ BT,
    const float* __restrict__ b0, const float* __restrict__ b1,
    const float* __restrict__ b2,
    const float* res,
    void* o0, void* o1, void* o2,
    const int M, const int N, const int K)
{
    __shared__ unsigned short As[64 * 256];
    __shared__ unsigned short Bs[64 * 256];

    int bx, by; xcd_swz(bx, by);

    const int tid  = threadIdx.x;
    const int lane = tid & 63;
    const int w    = tid >> 6;
    const int m0   = by * 64;
    const int n0   = bx * 64;
    const int wm   = (w >> 1) * 32;
    const int wn   = (w & 1) * 32;
    const int l16  = lane & 15;
    const int g16  = lane >> 4;

    f32x4 acc[2][2] = {};

    const unsigned short* Abase = A  + (size_t)m0 * K;
    const unsigned short* Bbase = BT + (size_t)n0 * K;

    for (int k0 = 0; k0 < K; k0 += 256) {
        __syncthreads();                 // LDS reuse guard
#pragma unroll
        for (int it = 0; it < 8; ++it) {
            const int c  = it * 256 + tid;
            const int rc = c >> 5;                    // row 0..63 (32 chunks/row)
            const int gk = (c & 31) ^ (rc & 7);       // swizzled k-group
            __builtin_amdgcn_global_load_lds(
                (const __attribute__((address_space(1))) unsigned*)(Abase + (size_t)rc * K + k0 + gk * 8),
                (__attribute__((address_space(3))) unsigned*)(As + (size_t)(it * 256 + (w << 6)) * 8), 16, 0, 0);
        }
#pragma unroll
        for (int it = 0; it < 8; ++it) {
            const int c  = it * 256 + tid;
            const int rc = c >> 5;
            const int gk = (c & 31) ^ (rc & 7);
            __builtin_amdgcn_global_load_lds(
                (const __attribute__((address_space(1))) unsigned*)(Bbase + (size_t)rc * K + k0 + gk * 8),
                (__attribute__((address_space(3))) unsigned*)(Bs + (size_t)(it * 256 + (w << 6)) * 8), 16, 0, 0);
        }
        __syncthreads();                 // implicit vmcnt(0): tile landed

#pragma unroll
        for (int kk = 0; kk < 8; ++kk) {
            const int kf = kk * 4 + g16;            // k-group 0..31
            const int sw = (kf ^ (l16 & 7)) * 8;    // swizzled ushort offset
            bf16x8 a[2], b[2];
#pragma unroll
            for (int t = 0; t < 2; ++t)
                a[t] = *(const bf16x8*)&As[(wm + t * 16 + l16) * 256 + sw];
#pragma unroll
            for (int t = 0; t < 2; ++t)
                b[t] = *(const bf16x8*)&Bs[(wn + t * 16 + l16) * 256 + sw];
#pragma unroll
            for (int i = 0; i < 2; ++i)
#pragma unroll
                for (int j = 0; j < 2; ++j)
                    acc[i][j] = __builtin_amdgcn_mfma_f32_16x16x32_bf16(a[i], b[j], acc[i][j], 0, 0, 0);
        }
    }

    if (OBF || SPLIT) {
        __syncthreads();
        unsigned short* Eb = ((w < 2) ? As : Bs) + (w & 1) * 1024;
        const int row16 = lane >> 2;
        const int cg    = lane & 3;

        const int gnb   = n0 + wn;
        const int which = SPLIT ? (gnb >> 9) : 0;
        const int lnb   = SPLIT ? (gnb & 511) : gnb;
        const int ldo   = SPLIT ? 512 : N;
        unsigned short* oo = SPLIT
            ? ((which == 0) ? (unsigned short*)o0 : (which == 1) ? (unsigned short*)o1 : (unsigned short*)o2)
            : (unsigned short*)o0;
        const float* bb = SPLIT ? ((which == 0) ? b0 : (which == 1) ? b1 : b2) : b0;
        const float scale = (SPLIT && which == 0) ? 0.125f : 1.0f;

#pragma unroll
        for (int i = 0; i < 2; ++i) {
#pragma unroll
            for (int j = 0; j < 2; ++j) {
                const float bv = bb[lnb + j * 16 + l16];
#pragma unroll
                for (int r = 0; r < 4; ++r) {
                    float cv = acc[i][j][r] + bv;
                    if (ACT) cv = gelu_exact(cv);
                    if (SPLIT) cv *= scale;
                    Eb[(g16 * 4 + r) * 40 + j * 16 + l16] = f2bf(cv);
                }
            }
            const int grow0 = m0 + wm + i * 16 + row16;
#pragma unroll
            for (int s = 0; s < 2; ++s) {
                ushort4 t4 = *(const ushort4*)&Eb[row16 * 40 + s * 16 + cg * 4];
                *(ushort4*)&oo[(size_t)grow0 * ldo + lnb + s * 16 + cg * 4] = t4;
            }
        }
        return;
    }

    // fp32 out epilogue (scalar 4B stores = full 64B runs per 16 lanes)
#pragma unroll
    for (int i = 0; i < 2; ++i) {
        const int gmb = m0 + wm + i * 16 + g16 * 4;
#pragma unroll
        for (int j = 0; j < 2; ++j) {
            const int gn = n0 + wn + j * 16 + l16;
            const float bv = b0[gn];
#pragma unroll
            for (int r = 0; r < 4; ++r) {
                float cv = acc[i][j][r] + bv;
                if (ACT) cv = gelu_exact(cv);
                if (RES) cv += res[(size_t)(gmb + r) * 512 + gn];
                ((float*)o0)[(size_t)(gmb + r) * N + gn] = cv;
            }
        }
    }
}

// ---------------------------------------------------------------------------
// bf16 MFMA GEMM, 128xBN tile, BK=128 (R6-proven). BN=64 (QKV) / 128 (up).
// ---------------------------------------------------------------------------
template<int ACT, int RES, int OBF, int SPLIT, int BN>
__global__ __launch_bounds__(256) void mm128_k(
    const unsigned short* __restrict__ A, const unsigned short* __restrict__ BT,
    const float* __restrict__ b0, const float* __restrict__ b1,
    const float* __restrict__ b2,
    const float* res,
    void* o0, void* o1, void* o2,
    const int M, const int N, const int K)
{
    constexpr int NJ = BN / 32;           // j-frags per wave (2 or 4)

    __shared__ unsigned short As[128 * 128];
    __shared__ unsigned short Bs[BN * 128];

    int bx, by; xcd_swz(bx, by);

    const int tid  = threadIdx.x;
    const int lane = tid & 63;
    const int w    = tid >> 6;
    const int m0   = by * 128;
    const int n0   = bx * BN;
    const int wm   = (w >> 1) * 64;       // 0 or 64
    const int wn   = (w & 1) * (BN / 2);
    const int l16  = lane & 15;
    const int g16  = lane >> 4;

    f32x4 acc[4][NJ] = {};

    const unsigned short* Abase = A  + (size_t)m0 * K;
    const unsigned short* Bbase = BT + (size_t)n0 * K;

    for (int k0 = 0; k0 < K; k0 += 128) {
        __syncthreads();
#pragma unroll
        for (int it = 0; it < 8; ++it) {
            const int c  = it * 256 + tid;
            const int rc = c >> 4;                    // 16 chunks/row
            const int gk = (c & 15) ^ (rc & 7);
            __builtin_amdgcn_global_load_lds(
                (const __attribute__((address_space(1))) unsigned*)(Abase + (size_t)rc * K + k0 + gk * 8),
                (__attribute__((address_space(3))) unsigned*)(As + (size_t)(it * 256 + (w << 6)) * 8), 16, 0, 0);
        }
#pragma unroll
        for (int it = 0; it < NJ * 2; ++it) {
            const int c  = it * 256 + tid;
            const int rc = c >> 4;
            const int gk = (c & 15) ^ (rc & 7);
            __builtin_amdgcn_global_load_lds(
                (const __attribute__((address_space(1))) unsigned*)(Bbase + (size_t)rc * K + k0 + gk * 8),
                (__attribute__((address_space(3))) unsigned*)(Bs + (size_t)(it * 256 + (w << 6)) * 8), 16, 0, 0);
        }
        __syncthreads();

#pragma unroll
        for (int kk = 0; kk < 4; ++kk) {
            const int kf = kk * 4 + g16;            // k-group 0..15
            const int sw = (kf ^ (l16 & 7)) * 8;    // swizzled ushort offset
            bf16x8 a[4], b[NJ];
#pragma unroll
            for (int t = 0; t < 4; ++t)
                a[t] = *(const bf16x8*)&As[(wm + t * 16 + l16) * 128 + sw];
#pragma unroll
            for (int t = 0; t < NJ; ++t)
                b[t] = *(const bf16x8*)&Bs[(wn + t * 16 + l16) * 128 + sw];
#pragma unroll
            for (int i = 0; i < 4; ++i)
#pragma unroll
                for (int j = 0; j < NJ; ++j)
                    acc[i][j] = __builtin_amdgcn_mfma_f32_16x16x32_bf16(a[i], b[j], acc[i][j], 0, 0, 0);
        }
    }

    if (OBF || SPLIT) {
        __syncthreads();
        constexpr int WC  = NJ * 16;          // wave cols (32 or 64)
        constexpr int EST = WC + 8;           // Eb stride (pad breaks conflicts)
        constexpr int LPR = WC / 4;           // lanes per row in store
        constexpr int RPI = 64 / LPR;         // rows per store instruction
        unsigned short* Eb = As + w * (16 * EST);
        const int erow = lane / LPR;
        const int ecol = (lane % LPR) * 4;

        const int gnb   = n0 + wn;
        const int which = SPLIT ? (gnb >> 9) : 0;
        const int lnb   = SPLIT ? (gnb & 511) : gnb;
        const int ldo   = SPLIT ? 512 : N;
        unsigned short* oo = SPLIT
            ? ((which == 0) ? (unsigned short*)o0 : (which == 1) ? (unsigned short*)o1 : (unsigned short*)o2)
            : (unsigned short*)o0;
        const float* bb = SPLIT ? ((which == 0) ? b0 : (which == 1) ? b1 : b2) : b0;
        const float scale = (SPLIT && which == 0) ? 0.125f : 1.0f;

#pragma unroll
        for (int i = 0; i < 4; ++i) {
#pragma unroll
            for (int j = 0; j < NJ; ++j) {
                const float bv = bb[lnb + j * 16 + l16];
#pragma unroll
                for (int r = 0; r < 4; ++r) {
                    float cv = acc[i][j][r] + bv;
                    if (ACT) cv = gelu_exact(cv);
                    if (SPLIT) cv *= scale;
                    Eb[(g16 * 4 + r) * EST + j * 16 + l16] = f2bf(cv);
                }
            }
            const int grow0 = m0 + wm + i * 16;
#pragma unroll
            for (int s = 0; s < NJ; ++s) {
                ushort4 t4 = *(const ushort4*)&Eb[(s * RPI + erow) * EST + ecol];
                *(ushort4*)&oo[(size_t)(grow0 + s * RPI + erow) * ldo + lnb + ecol] = t4;
            }
        }
        return;
    }

    // fp32 out epilogue
#pragma unroll
    for (int i = 0; i < 4; ++i) {
        const int gmb = m0 + wm + i * 16 + g16 * 4;
#pragma unroll
        for (int j = 0; j < NJ; ++j) {
            const int gn = n0 + wn + j * 16 + l16;
            const float bv = b0[gn];
#pragma unroll
            for (int r = 0; r < 4; ++r) {
                float cv = acc[i][j][r] + bv;
                if (ACT) cv = gelu_exact(cv);
                if (RES) cv += res[(size_t)(gmb + r) * 512 + gn];
                ((float*)o0)[(size_t)(gmb + r) * N + gn] = cv;
            }
        }
    }
}

// ---------------------------------------------------------------------------
// Fused prologue: weight transposes + spikes convert + RoPE cos/sin table.
// Table: rope_tab[row*32+d] = {cos(ts[row]*f_d), sin(ts[row]*f_d)}, 1 MB fp32,
// shared by all heads AND all 4 layers -> kills ~all staging trig in attn
// (K windows overlap 3x between q-tiles; table makes the recompute free).
// ---------------------------------------------------------------------------
__global__ __launch_bounds__(256) void prep_k(
    const float* __restrict__ spikes,
    const float* __restrict__ embed_w, const float* __restrict__ proj_w,
    const float* __restrict__ Wq, const float* __restrict__ Wk,
    const float* __restrict__ Wv, const float* __restrict__ Wo,
    const float* __restrict__ up_w, const float* __restrict__ down_w,
    const int* __restrict__ ts,
    unsigned short* __restrict__ spbf,
    unsigned short* __restrict__ embT, unsigned short* __restrict__ projT,
    unsigned short* __restrict__ qkvT, unsigned short* __restrict__ woT,
    unsigned short* __restrict__ upT, unsigned short* __restrict__ downT,
    float2* __restrict__ rope_tab)
{
    const int idx = blockIdx.x;
    const int tid = threadIdx.x;

    if (idx >= 3376) {  // RoPE table: 32 blocks x 4096 entries (4096 rows x 32 d)
        const int e0 = (idx - 3376) * 4096 + tid * 16;
#pragma unroll
        for (int i = 0; i < 16; ++i) {
            const int e = e0 + i;
            const int row = e >> 5, d = e & 31;
            const float tstamp = (float)ts[row];
            const float freq = __expf(-0.2878231366242558f * (float)d);
            const float ang = tstamp * freq;
            rope_tab[e] = make_float2(__cosf(ang), __sinf(ang));
        }
        return;
    }

    if (idx >= 3120) {  // spikes fp32->bf16: 256 blocks x 4096 elems
        const int base = (idx - 3120) * 4096 + tid * 16;
#pragma unroll
        for (int s = 0; s < 4; ++s) {
            float4 v = *(const float4*)&spikes[base + s * 4];
            ushort4 o = {f2bf(v.x), f2bf(v.y), f2bf(v.z), f2bf(v.w)};
            *(ushort4*)&spbf[base + s * 4] = o;
        }
        return;
    }

    const float* src; unsigned short* dst; int R, Cc, t;
    if (idx < 16)      { src = embed_w; dst = embT;  R = C_; Cc = D_; t = idx; }
    else if (idx < 48) { src = proj_w;  dst = projT; R = D_; Cc = H_; t = idx - 16; }
    else if (idx < 816) {
        const int j = idx - 48;        // 0..767: Wq | Wk | Wv, 4 layers x 64 tiles
        const int wsel = j >> 8;
        const int l = (j & 255) >> 6;
        t = j & 63;
        src = ((wsel == 0) ? Wq : (wsel == 1) ? Wk : Wv) + (size_t)l * H_ * H_;
        dst = qkvT + (size_t)l * 3 * H_ * H_ + (size_t)wsel * H_ * H_;
        R = H_; Cc = H_;
    } else if (idx < 1072) {
        const int j = idx - 816; const int l = j >> 6; t = j & 63;
        src = Wo + (size_t)l * H_ * H_; dst = woT + (size_t)l * H_ * H_;
        R = H_; Cc = H_;
    } else if (idx < 2096) {
        const int j = idx - 1072; const int l = j >> 8; t = j & 255;
        src = up_w + (size_t)l * H_ * INTER_; dst = upT + (size_t)l * INTER_ * H_;
        R = H_; Cc = INTER_;
    } else {
        const int j = idx - 2096; const int l = j >> 8; t = j & 255;
        src = down_w + (size_t)l * INTER_ * H_; dst = downT + (size_t)l * H_ * INTER_;
        R = INTER_; Cc = H_;
    }
    const int ntx = Cc >> 6;
    const int c0 = (t % ntx) * 64, r0 = (t / ntx) * 64;

    __shared__ float tile[64][65];
    const int tr = tid >> 4, tc = (tid & 15) * 4;
#pragma unroll
    for (int i = 0; i < 4; ++i) {
        float4 v = *(const float4*)&src[(size_t)(r0 + tr + i * 16) * Cc + c0 + tc];
        tile[tr + i * 16][tc + 0] = v.x;
        tile[tr + i * 16][tc + 1] = v.y;
        tile[tr + i * 16][tc + 2] = v.z;
        tile[tr + i * 16][tc + 3] = v.w;
    }
    __syncthreads();
#pragma unroll
    for (int i = 0; i < 4; ++i) {
        const int n = tr + i * 16;
        ushort4 o;
        o.x = f2bf(tile[tc + 0][n]);
        o.y = f2bf(tile[tc + 1][n]);
        o.z = f2bf(tile[tc + 2][n]);
        o.w = f2bf(tile[tc + 3][n]);
        *(ushort4*)&dst[(size_t)(c0 + n) * R + r0 + tc] = o;
    }
}

// ---------------------------------------------------------------------------
// LayerNorm over H=512, bf16 output. One row per WAVE (4 rows/block):
// pure shfl reduction -- zero barriers, zero LDS (was 4 syncthreads/row).
// ---------------------------------------------------------------------------
__global__ __launch_bounds__(256) void ln_k(
    const float* __restrict__ x, const float* __restrict__ g,
    const float* __restrict__ b, unsigned short* __restrict__ out)
{
    const int wave = threadIdx.x >> 6;
    const int lane = threadIdx.x & 63;
    const int row  = blockIdx.x * 4 + wave;
    const float* xr = x + (size_t)row * H_;
    const int c0 = lane * 8;

    float4 a0 = *(const float4*)&xr[c0];
    float4 a1 = *(const float4*)&xr[c0 + 4];

    float s = a0.x + a0.y + a0.z + a0.w + a1.x + a1.y + a1.z + a1.w;
#pragma unroll
    for (int off = 32; off; off >>= 1) s += __shfl_xor(s, off);
    const float mean = s * (1.0f / (float)H_);

    float d[8];
    d[0] = a0.x - mean; d[1] = a0.y - mean; d[2] = a0.z - mean; d[3] = a0.w - mean;
    d[4] = a1.x - mean; d[5] = a1.y - mean; d[6] = a1.z - mean; d[7] = a1.w - mean;
    float q = 0.0f;
#pragma unroll
    for (int j = 0; j < 8; ++j) q += d[j] * d[j];
#pragma unroll
    for (int off = 32; off; off >>= 1) q += __shfl_xor(q, off);
    const float rstd = rsqrtf(q * (1.0f / (float)H_) + 1e-5f);

    float4 g0 = *(const float4*)&g[c0];
    float4 g1 = *(const float4*)&g[c0 + 4];
    float4 b0 = *(const float4*)&b[c0];
    float4 b1 = *(const float4*)&b[c0 + 4];

    ushort4 o0, o1;
    o0.x = f2bf(d[0] * rstd * g0.x + b0.x);
    o0.y = f2bf(d[1] * rstd * g0.y + b0.y);
    o0.z = f2bf(d[2] * rstd * g0.z + b0.z);
    o0.w = f2bf(d[3] * rstd * g0.w + b0.w);
    o1.x = f2bf(d[4] * rstd * g1.x + b1.x);
    o1.y = f2bf(d[5] * rstd * g1.y + b1.y);
    o1.z = f2bf(d[6] * rstd * g1.z + b1.z);
    o1.w = f2bf(d[7] * rstd * g1.w + b1.w);
    *(ushort4*)&out[(size_t)row * H_ + c0]     = o0;
    *(ushort4*)&out[(size_t)row * H_ + c0 + 4] = o1;
}

// ---------------------------------------------------------------------------
// MFMA banded attention. RoPE via precomputed cos/sin table (no trig in the
// hot path); Q built in registers (R5); LDS 52 KB -> 3 blocks/CU.
// ---------------------------------------------------------------------------
#define AWIN 192
#define AKS 72
#define AVS 200

__global__ __launch_bounds__(256) void attn_k(
    const unsigned short* __restrict__ q, const unsigned short* __restrict__ k,
    const unsigned short* __restrict__ v, const int* __restrict__ smask,
    const float2* __restrict__ rope_tab, unsigned short* __restrict__ o)
{
    __shared__ unsigned short Ks[AWIN * AKS];   // reused as Pb after S-pass
    __shared__ unsigned short Vt[64 * AVS];
    unsigned short* const Pb = Ks;              // 64*AVS = 12800 <= 13824

    const int blk = blockIdx.x;
    const int qt = blk & 15;
    const int h  = (blk >> 4) & 7;
    const int b  = blk >> 7;
    const int tid  = threadIdx.x;
    const int lane = tid & 63;
    const int w    = tid >> 6;
    const int l16  = lane & 15;
    const int g16  = lane >> 4;

    const int qlo = qt * 64;
    const int klo = (qlo >= CB_) ? (qlo - CB_) : 0;
    const int tb  = b * 1024;

    // ---- Q with RoPE, straight into the a-frag registers ----
    bf16x8 qa0, qa1;
    {
        const int qrow = w * 16 + l16;
        const unsigned short* gq = q + ((size_t)(tb + qlo + qrow)) * 512 + h * 64;
        ush8 lo = *(const ush8*)&gq[g16 * 8];
        ush8 hi = *(const ush8*)&gq[g16 * 8 + 32];
        const float2* tr = rope_tab + (size_t)(tb + qlo + qrow) * 32 + g16 * 8;
#pragma unroll
        for (int j = 0; j < 8; ++j) {
            const float2 cs = tr[j];
            const float v1 = bf2f(lo[j]);
            const float v2 = bf2f(hi[j]);
            ((unsigned short*)&qa0)[j] = f2bf(v1 * cs.x - v2 * cs.y);
            ((unsigned short*)&qa1)[j] = f2bf(v2 * cs.x + v1 * cs.y);
        }
    }

    // ---- stage K with RoPE (table) ----
    {
        const unsigned short* gk = k + ((size_t)(tb + klo)) * 512 + h * 64;
        for (int c = tid; c < AWIN * 8; c += 256) {
            const int row = c >> 3, c4 = (c & 7) * 4;
            ushort4 lo = *(const ushort4*)&gk[(size_t)row * 512 + c4];
            ushort4 hi = *(const ushort4*)&gk[(size_t)row * 512 + c4 + 32];
            const float2* tr = rope_tab + (size_t)(tb + klo + row) * 32 + c4;
            ushort4 olo, ohi;
#pragma unroll
            for (int j2 = 0; j2 < 4; ++j2) {
                const float2 cs = tr[j2];
                const float v1 = bf2f(((const unsigned short*)&lo)[j2]);
                const float v2 = bf2f(((const unsigned short*)&hi)[j2]);
                ((unsigned short*)&olo)[j2] = f2bf(v1 * cs.x - v2 * cs.y);
                ((unsigned short*)&ohi)[j2] = f2bf(v2 * cs.x + v1 * cs.y);
            }
            *(ushort4*)&Ks[row * AKS + c4]      = olo;
            *(ushort4*)&Ks[row * AKS + c4 + 32] = ohi;
        }
    }
    // ---- stage V (transposed into LDS) ----
    {
        const unsigned short* gv = v + ((size_t)(tb + klo)) * 512 + h * 64;
        for (int c = tid; c < AWIN * 16; c += 256) {
            const int row = c >> 4, c4 = (c & 15) * 4;
            ushort4 vv = *(const ushort4*)&gv[(size_t)row * 512 + c4];
            Vt[(c4 + 0) * AVS + row] = vv.x;
            Vt[(c4 + 1) * AVS + row] = vv.y;
            Vt[(c4 + 2) * AVS + row] = vv.z;
            Vt[(c4 + 3) * AVS + row] = vv.w;
        }
    }
    __syncthreads();

    // ---- S = Q @ K^T ----
    f32x4 accs[12];
#pragma unroll
    for (int t = 0; t < 12; ++t) {
        const bf16x8 b0 = *(const bf16x8*)&Ks[(t * 16 + l16) * AKS + g16 * 8];
        const bf16x8 b1 = *(const bf16x8*)&Ks[(t * 16 + l16) * AKS + 32 + g16 * 8];
        f32x4 c = {};
        c = __builtin_amdgcn_mfma_f32_16x16x32_bf16(qa0, b0, c, 0, 0, 0);
        c = __builtin_amdgcn_mfma_f32_16x16x32_bf16(qa1, b1, c, 0, 0, 0);
        accs[t] = c;
    }

    // ---- softmax in registers ----
    bool mk[12];
    int  jj[12];
#pragma unroll
    for (int t = 0; t < 12; ++t) {
        jj[t] = klo + t * 16 + l16;
        mk[t] = smask[tb + jj[t]] > 0;
    }

    float rs[4];
#pragma unroll
    for (int r = 0; r < 4; ++r) {
        const int i = qlo + 16 * w + g16 * 4 + r;
        float mx = -1e30f;
#pragma unroll
        for (int t = 0; t < 12; ++t) {
            const bool val = mk[t] && (jj[t] >= i - CB_) && (jj[t] <= i);
            mx = fmaxf(mx, val ? accs[t][r] : -1e30f);
        }
        mx = fmaxf(mx, __shfl_xor(mx, 1));
        mx = fmaxf(mx, __shfl_xor(mx, 2));
        mx = fmaxf(mx, __shfl_xor(mx, 4));
        mx = fmaxf(mx, __shfl_xor(mx, 8));
        float sum = 0.0f;
#pragma unroll
        for (int t = 0; t < 12; ++t) {
            const bool val = mk[t] && (jj[t] >= i - CB_) && (jj[t] <= i);
            const float p = val ? __expf(accs[t][r] - mx) : 0.0f;
            accs[t][r] = p;
            sum += p;
        }
        sum += __shfl_xor(sum, 1);
        sum += __shfl_xor(sum, 2);
        sum += __shfl_xor(sum, 4);
        sum += __shfl_xor(sum, 8);
        rs[r] = 1.0f / sum;
    }

    // Ks dead from here; Pb aliases it.
    __syncthreads();

    // ---- P -> LDS ----
#pragma unroll
    for (int t = 0; t < 12; ++t)
#pragma unroll
        for (int r = 0; r < 4; ++r)
            Pb[(16 * w + g16 * 4 + r) * AVS + t * 16 + l16] = f2bf(accs[t][r]);

    // ---- O = P @ V ----
    f32x4 acco[4];
#pragma unroll
    for (int nt = 0; nt < 4; ++nt) {
        f32x4 c = {};
#pragma unroll
        for (int ks = 0; ks < 6; ++ks) {
            const bf16x8 a = *(const bf16x8*)&Pb[(16 * w + l16) * AVS + ks * 32 + g16 * 8];
            const bf16x8 bb = *(const bf16x8*)&Vt[(nt * 16 + l16) * AVS + ks * 32 + g16 * 8];
            c = __builtin_amdgcn_mfma_f32_16x16x32_bf16(a, bb, c, 0, 0, 0);
        }
        acco[nt] = c;
    }

    // ---- stage O into Pb, vector store ----
    __syncthreads();
#pragma unroll
    for (int nt = 0; nt < 4; ++nt)
#pragma unroll
        for (int r = 0; r < 4; ++r)
            Pb[(16 * w + g16 * 4 + r) * AVS + nt * 16 + l16] = f2bf(acco[nt][r] * rs[r]);

    const int row16 = lane >> 2, cg = lane & 3;
    const int grow = tb + qlo + 16 * w + row16;
#pragma unroll
    for (int s = 0; s < 4; ++s) {
        ushort4 t4 = *(const ushort4*)&Pb[(16 * w + row16) * AVS + s * 16 + cg * 4];
        *(ushort4*)&o[(size_t)grow * 512 + h * 64 + s * 16 + cg * 4] = t4;
    }
}

// ---------------------------------------------------------------------------
extern "C" void kernel_launch(void* const* d_in, const int* in_sizes, int n_in,
                              void* d_out, int out_size, void* d_ws, size_t ws_size,
                              hipStream_t stream)
{
    const float* spikes  = (const float*)d_in[0];
    const int*   smask   = (const int*)d_in[1];
    const int*   ts      = (const int*)d_in[2];
    const float* embed_w = (const float*)d_in[3];
    const float* embed_b = (const float*)d_in[4];
    const float* proj_w  = (const float*)d_in[5];
    const float* proj_b  = (const float*)d_in[6];
    const float* ln1_g   = (const float*)d_in[7];
    const float* ln1_b   = (const float*)d_in[8];
    const float* Wq      = (const float*)d_in[9];
    const float* bq      = (const float*)d_in[10];
    const float* Wk      = (const float*)d_in[11];
    const float* bk      = (const float*)d_in[12];
    const float* Wv      = (const float*)d_in[13];
    const float* bv      = (const float*)d_in[14];
    const float* Wo      = (const float*)d_in[15];
    const float* bo      = (const float*)d_in[16];
    const float* ln2_g   = (const float*)d_in[17];
    const float* ln2_b   = (const float*)d_in[18];
    const float* up_w    = (const float*)d_in[19];
    const float* up_b    = (const float*)d_in[20];
    const float* down_w  = (const float*)d_in[21];
    const float* down_b  = (const float*)d_in[22];

    const int M = B_ * T_;  // 4096

    char* p = (char*)d_ws;
    float* x = (float*)p;                       p += (size_t)M * H_ * 4;
    unsigned short* qb  = (unsigned short*)p;   p += (size_t)M * H_ * 2;
    unsigned short* kb  = (unsigned short*)p;   p += (size_t)M * H_ * 2;
    unsigned short* vb  = (unsigned short*)p;   p += (size_t)M * H_ * 2;
    unsigned short* hbf = (unsigned short*)p;   p += (size_t)M * H_ * 2;
    unsigned short* obf = (unsigned short*)p;   p += (size_t)M * H_ * 2;
    unsigned short* ibf = (unsigned short*)p;   p += (size_t)M * INTER_ * 2;
    unsigned short* tbf = (unsigned short*)p;   p += (size_t)M * D_ * 2;
    unsigned short* spbf  = (unsigned short*)p; p += (size_t)M * C_ * 2;
    unsigned short* embT  = (unsigned short*)p; p += (size_t)D_ * C_ * 2;
    unsigned short* projT = (unsigned short*)p; p += (size_t)H_ * D_ * 2;
    unsigned short* qkvT  = (unsigned short*)p; p += (size_t)L_ * 3 * H_ * H_ * 2;
    unsigned short* woT   = (unsigned short*)p; p += (size_t)L_ * H_ * H_ * 2;
    unsigned short* upT   = (unsigned short*)p; p += (size_t)L_ * INTER_ * H_ * 2;
    unsigned short* downT = (unsigned short*)p; p += (size_t)L_ * H_ * INTER_ * 2;
    float2* rope_tab = (float2*)p;              p += (size_t)M * 32 * sizeof(float2);

    // ---- fused prologue: weight transposes + spikes convert + rope table
    prep_k<<<3408, 256, 0, stream>>>(
        spikes, embed_w, proj_w, Wq, Wk, Wv, Wo, up_w, down_w, ts,
        spbf, embT, projT, qkvT, woT, upT, downT, rope_tab);

    // ---- embedding ----  (K=256: single drain per tile)
    mm64_k<1, 0, 1, 0><<<dim3(D_ / 64, M / 64), 256, 0, stream>>>(
        spbf, embT, embed_b, nullptr, nullptr, nullptr,
        tbf, nullptr, nullptr, M, D_, C_);
    mm64_k<0, 0, 0, 0><<<dim3(H_ / 64, M / 64), 256, 0, stream>>>(
        tbf, projT, proj_b, nullptr, nullptr, nullptr,
        x, nullptr, nullptr, M, H_, D_);

    for (int l = 0; l < L_; ++l) {
        const unsigned short* qkvT_l = qkvT + (size_t)l * 3 * H_ * H_;
        const unsigned short* woT_l  = woT  + (size_t)l * H_ * H_;
        const unsigned short* upT_l  = upT  + (size_t)l * INTER_ * H_;
        const unsigned short* dnT_l  = downT + (size_t)l * H_ * INTER_;

        ln_k<<<M / 4, 256, 0, stream>>>(x, ln1_g + l * H_, ln1_b + l * H_, hbf);

        // fused QKV + bias (+0.125 q scale): 128x64 BK=128, grid 768, 4 drains
        mm128_k<0, 0, 1, 1, 64><<<dim3((3 * H_) / 64, M / 128), 256, 0, stream>>>(
            hbf, qkvT_l, bq + l * H_, bk + l * H_, bv + l * H_, nullptr,
            qb, kb, vb, M, 3 * H_, H_);

        // attention (RoPE via table; Q in registers; 3 blocks/CU)
        attn_k<<<B_ * NH_ * (T_ / 64), 256, 0, stream>>>(qb, kb, vb, smask,
                                                         rope_tab, obf);

        // x = x + obuf @ Wo + bo  (64x64 BK=256: 2 drains)
        mm64_k<0, 1, 0, 0><<<dim3(H_ / 64, M / 64), 256, 0, stream>>>(
            obf, woT_l, bo + l * H_, nullptr, nullptr, x,
            x, nullptr, nullptr, M, H_, H_);

        ln_k<<<M / 4, 256, 0, stream>>>(x, ln2_g + l * H_, ln2_b + l * H_, hbf);

        // inter = gelu(h @ up_w + b)  (128x128 BK=128: grid 512 = 2/CU, 4 drains)
        mm128_k<1, 0, 1, 0, 128><<<dim3(INTER_ / 128, M / 128), 256, 0, stream>>>(
            hbf, upT_l, up_b + l * INTER_, nullptr, nullptr, nullptr,
            ibf, nullptr, nullptr, M, INTER_, H_);

        // x = x + inter @ down_w + b  (64x64 BK=256: 8 drains)
        float* dst = (l == L_ - 1) ? (float*)d_out : x;
        mm64_k<0, 1, 0, 0><<<dim3(H_ / 64, M / 64), 256, 0, stream>>>(
            ibf, dnT_l, down_b + l * H_, nullptr, nullptr, x,
            dst, nullptr, nullptr, M, H_, INTER_);
    }
}